// Round 6
// baseline (181.851 us; speedup 1.0000x reference)
//
#include <hip/hip_runtime.h>
#include <hip/hip_bf16.h>

// ResContextBlock R6: R5 structure (dense center-tap bf16 MFMA + LDS-batched
// off-center hits) with: native v_cvt_pk bf16 converts, uniform-branch inject
// (switch on SGPR jj/jp), hitbuf/stage LDS union (17408B -> more waves/CU).

typedef __attribute__((ext_vector_type(8))) short bf16x8;
typedef __attribute__((ext_vector_type(4))) float f32x4;
typedef unsigned long long ull;

#define EPSF 1e-5f
#define REP8 0x0101010101010101ull

__device__ __forceinline__ unsigned short f2bf(float f) {
    union { __hip_bfloat16 h; unsigned short u; } cv;
    cv.h = __float2bfloat16(f);   // RNE; compiler emits v_cvt_pk_bf16_f32
    return cv.u;
}
__device__ __forceinline__ unsigned pkbf(float lo, float hi) {
    return (unsigned)f2bf(lo) | ((unsigned)f2bf(hi) << 16);
}

// ---------- prep: pack W1,W3 -> bf16 B-frags for ALL 9 ks ----------
__global__ void prep_kernel(const float* __restrict__ W1, const float* __restrict__ W3,
                            unsigned short* __restrict__ Wb1, unsigned short* __restrict__ Wb3)
{
    int i = blockIdx.x * 256 + threadIdx.x;
    if (i >= 2 * 9 * 2048) return;
    const float* W = i < 9 * 2048 ? W1 : W3;
    unsigned short* Wb = i < 9 * 2048 ? Wb1 : Wb3;
    int pp = i < 9 * 2048 ? i : i - 9 * 2048;
    int k = pp >> 11, rest = pp & 2047;
    int t = (rest >> 9) & 3, lane = (rest >> 3) & 63, j = rest & 7;
    int c = (lane >> 4) * 8 + j;
    int d = t * 16 + (lane & 15);
    Wb[pp] = f2bf(W[(size_t)(k * 32 + c) * 64 + d]);
}

// ---------- fused conv1+conv3 (CIN=32 fp32 in, bf16 y out) ----------
__global__ __launch_bounds__(256, 6)
void conv13_kernel(const float* __restrict__ x,
                   const int* __restrict__ nbrA, const int* __restrict__ nbrB,
                   const unsigned short* __restrict__ WbA,
                   const unsigned short* __restrict__ WbB,
                   unsigned short* __restrict__ yA, unsigned short* __restrict__ yB,
                   float* __restrict__ part,    // [tile][256]
                   int n_vox)
{
    const int lane = threadIdx.x & 63;
    const int wave = threadIdx.x >> 6;
    // per-wave 4352B: hit staging (A rows @0, B rows @2048; 4KB) OR
    // epilogue stage ([16][68] floats = 4352B) -- disjoint lifetimes.
    __shared__ __align__(16) char smem[4][4352];
    char* my = smem[wave];
    const int c15 = lane & 15, g16 = lane >> 4;
    const int j7 = lane & 7, kk = j7 + (j7 >= 4 ? 1 : 0), vv = lane >> 3;
    const int v16 = blockIdx.x * 64 + wave * 16;

    // probes
    const size_t r0 = (size_t)(v16 + vv) * 9 + kk;
    const size_t r1 = (size_t)(v16 + 8 + vv) * 9 + kk;
    int pA0 = nbrA[r0], pA1 = nbrA[r1];
    int pB0 = nbrB[r0], pB1 = nbrB[r1];

    // dense A-frag (fp32 -> bf16)
    const float* xr = x + (size_t)(v16 + c15) * 32 + g16 * 8;
    float4 x0 = *reinterpret_cast<const float4*>(xr);
    float4 x1 = *reinterpret_cast<const float4*>(xr + 4);

    bf16x8 bA[4], bB[4];
    #pragma unroll
    for (int t = 0; t < 4; ++t) {
        bA[t] = *reinterpret_cast<const bf16x8*>(WbA + (size_t)((4*4+t)*64 + lane) * 8);
        bB[t] = *reinterpret_cast<const bf16x8*>(WbB + (size_t)((4*4+t)*64 + lane) * 8);
    }
    bf16x8 af;
    af[0]=(short)f2bf(x0.x); af[1]=(short)f2bf(x0.y); af[2]=(short)f2bf(x0.z); af[3]=(short)f2bf(x0.w);
    af[4]=(short)f2bf(x1.x); af[5]=(short)f2bf(x1.y); af[6]=(short)f2bf(x1.z); af[7]=(short)f2bf(x1.w);

    f32x4 accA[4], accB[4];
    #pragma unroll
    for (int t = 0; t < 4; ++t) { f32x4 z = {0.f,0.f,0.f,0.f}; accA[t] = z; accB[t] = z; }
    #pragma unroll
    for (int t = 0; t < 4; ++t) {
        accA[t] = __builtin_amdgcn_mfma_f32_16x16x32_bf16(af, bA[t], accA[t], 0, 0, 0);
        accB[t] = __builtin_amdgcn_mfma_f32_16x16x32_bf16(af, bB[t], accB[t], 0, 0, 0);
    }

    ull mA0 = __ballot(pA0 < n_vox), mA1 = __ballot(pA1 < n_vox);
    ull mB0 = __ballot(pB0 < n_vox), mB1 = __ballot(pB1 < n_vox);
    const int nhA = __popcll(mA0) + __popcll(mA1);
    const int nhB = __popcll(mB0) + __popcll(mB1);

    auto walksel = [&](ull M, int preg, int slot, int base, int& sel0, int& sel1) {
        while (M) {
            int b = __builtin_ctzll(M); M &= M - 1;
            int src = __shfl(preg, b);
            int rs = slot - base;
            sel0 = ((lane >> 3) == rs)     ? src : sel0;
            sel1 = ((lane >> 3) == rs - 8) ? src : sel1;
            ++slot;
        }
        return slot;
    };
    auto stage2 = [&](int s0, int s1, int off4) {
        uint4 q0 = *reinterpret_cast<const uint4*>((const char*)x + (size_t)s0*128 + (lane&7)*16);
        uint4 q1 = *reinterpret_cast<const uint4*>((const char*)x + (size_t)s1*128 + (lane&7)*16);
        reinterpret_cast<uint4*>(my)[off4 + lane]      = q0;
        reinterpret_cast<uint4*>(my)[off4 + 64 + lane] = q1;
    };
    auto loadfrag = [&](int hbyte) {
        const float* hf = reinterpret_cast<const float*>(my + hbyte + c15 * 128 + g16 * 32);
        float4 f0 = *reinterpret_cast<const float4*>(hf);
        float4 f1 = *reinterpret_cast<const float4*>(hf + 4);
        bf16x8 h;
        h[0]=(short)f2bf(f0.x); h[1]=(short)f2bf(f0.y); h[2]=(short)f2bf(f0.z); h[3]=(short)f2bf(f0.w);
        h[4]=(short)f2bf(f1.x); h[5]=(short)f2bf(f1.y); h[6]=(short)f2bf(f1.z); h[7]=(short)f2bf(f1.w);
        return h;
    };
    auto kloop = [&](ull m0, ull m1, bf16x8 h, const unsigned short* Wb,
                     f32x4* acc, int base) {
        const int pref = __popcll(m0);
        for (int tap = 0; tap < 8; ++tap) {
            ull TM = REP8 << tap;
            ull k0 = m0 & TM, k1 = m1 & TM;
            if (!(k0 | k1)) continue;
            int k = tap + (tap >= 4 ? 1 : 0);
            bf16x8 bk[4];
            #pragma unroll
            for (int t = 0; t < 4; ++t)
                bk[t] = *reinterpret_cast<const bf16x8*>(Wb + (size_t)((k*4+t)*64 + lane) * 8);
            f32x4 ch[4];
            #pragma unroll
            for (int t = 0; t < 4; ++t) { f32x4 z = {0.f,0.f,0.f,0.f}; ch[t] = z; }
            #pragma unroll
            for (int t = 0; t < 4; ++t)
                ch[t] = __builtin_amdgcn_mfma_f32_16x16x32_bf16(h, bk[t], ch[t], 0, 0, 0);
            auto inj = [&](ull M, ull msrc, int spref, int vbase) {
                while (M) {
                    int b = __builtin_ctzll(M); M &= M - 1;
                    int slot = spref + __popcll(msrc & ((1ull << b) - 1ull));
                    int rs = slot - base;
                    if (rs < 0 || rs >= 16) continue;
                    int vb = vbase + (b >> 3);
                    int srclane = ((rs >> 2) << 4) + c15;        // uniform group + lane col
                    int jj = rs & 3, gp = vb >> 2, jp = vb & 3;  // all SGPR-uniform
                    float v0, v1, v2, v3;
                    switch (jj) {
                    case 0: v0=__shfl(ch[0][0],srclane); v1=__shfl(ch[1][0],srclane);
                            v2=__shfl(ch[2][0],srclane); v3=__shfl(ch[3][0],srclane); break;
                    case 1: v0=__shfl(ch[0][1],srclane); v1=__shfl(ch[1][1],srclane);
                            v2=__shfl(ch[2][1],srclane); v3=__shfl(ch[3][1],srclane); break;
                    case 2: v0=__shfl(ch[0][2],srclane); v1=__shfl(ch[1][2],srclane);
                            v2=__shfl(ch[2][2],srclane); v3=__shfl(ch[3][2],srclane); break;
                    default: v0=__shfl(ch[0][3],srclane); v1=__shfl(ch[1][3],srclane);
                             v2=__shfl(ch[2][3],srclane); v3=__shfl(ch[3][3],srclane); break;
                    }
                    bool mine = (g16 == gp);
                    float z0 = mine ? v0 : 0.f, z1 = mine ? v1 : 0.f;
                    float z2 = mine ? v2 : 0.f, z3 = mine ? v3 : 0.f;
                    switch (jp) {
                    case 0: acc[0][0]+=z0; acc[1][0]+=z1; acc[2][0]+=z2; acc[3][0]+=z3; break;
                    case 1: acc[0][1]+=z0; acc[1][1]+=z1; acc[2][1]+=z2; acc[3][1]+=z3; break;
                    case 2: acc[0][2]+=z0; acc[1][2]+=z1; acc[2][2]+=z2; acc[3][2]+=z3; break;
                    default: acc[0][3]+=z0; acc[1][3]+=z1; acc[2][3]+=z2; acc[3][3]+=z3; break;
                    }
                }
            };
            inj(k0, m0, 0, 0);
            inj(k1, m1, pref, 8);
        }
    };

    // batch-0 staging for BOTH tables
    {
        int sA0=0, sA1=0, sB0=0, sB1=0;
        int cA = walksel(mA0, pA0, 0, 0, sA0, sA1);
        walksel(mA1, pA1, cA, 0, sA0, sA1);
        int cB = walksel(mB0, pB0, 0, 0, sB0, sB1);
        walksel(mB1, pB1, cB, 0, sB0, sB1);
        stage2(sA0, sA1, 0);
        stage2(sB0, sB1, 128);
    }
    if (nhA) {
        bf16x8 hA = loadfrag(0);
        kloop(mA0, mA1, hA, WbA, accA, 0);
        for (int base = 16; base < nhA; base += 16) {
            int s0=0, s1=0;
            int c0 = walksel(mA0, pA0, 0, base, s0, s1);
            walksel(mA1, pA1, c0, base, s0, s1);
            stage2(s0, s1, 0);
            bf16x8 h = loadfrag(0);
            kloop(mA0, mA1, h, WbA, accA, base);
        }
    }
    if (nhB) {
        bf16x8 hB = loadfrag(2048);
        kloop(mB0, mB1, hB, WbB, accB, 0);
        for (int base = 16; base < nhB; base += 16) {
            int s0=0, s1=0;
            int c0 = walksel(mB0, pB0, 0, base, s0, s1);
            walksel(mB1, pB1, c0, base, s0, s1);
            stage2(s0, s1, 128);
            bf16x8 h = loadfrag(2048);
            kloop(mB0, mB1, h, WbB, accB, base);
        }
    }

    // epilogue (hitbuf lifetime over; reuse smem as [16][68] stage)
    float psA0[4], psA1[4], psB0[4], psB1[4];
    #pragma unroll
    for (int t = 0; t < 4; ++t) { psA0[t]=0.f; psA1[t]=0.f; psB0[t]=0.f; psB1[t]=0.f; }

    auto epi = [&](f32x4* acc, float* ps0, float* ps1, unsigned short* yo) {
        float* stg = reinterpret_cast<float*>(my);
        #pragma unroll
        for (int t = 0; t < 4; ++t) {
            const int col = t * 16 + c15;
            #pragma unroll
            for (int j = 0; j < 4; ++j) {
                float v = acc[t][j];
                v = v > 0.f ? v : 0.01f * v;
                ps0[t] += v;
                ps1[t] = fmaf(v, v, ps1[t]);
                stg[(g16 * 4 + j) * 68 + col] = v;
            }
        }
        const int mm = lane >> 2, cc0 = (lane & 3) * 16;
        float4 q0 = *reinterpret_cast<float4*>(&stg[mm * 68 + cc0]);
        float4 q1 = *reinterpret_cast<float4*>(&stg[mm * 68 + cc0 + 4]);
        float4 q2 = *reinterpret_cast<float4*>(&stg[mm * 68 + cc0 + 8]);
        float4 q3 = *reinterpret_cast<float4*>(&stg[mm * 68 + cc0 + 12]);
        uint4 o0, o1;
        o0.x = pkbf(q0.x, q0.y); o0.y = pkbf(q0.z, q0.w);
        o0.z = pkbf(q1.x, q1.y); o0.w = pkbf(q1.z, q1.w);
        o1.x = pkbf(q2.x, q2.y); o1.y = pkbf(q2.z, q2.w);
        o1.z = pkbf(q3.x, q3.y); o1.w = pkbf(q3.z, q3.w);
        uint4* dst = reinterpret_cast<uint4*>(yo + (size_t)(v16 + mm) * 64 + cc0);
        dst[0] = o0; dst[1] = o1;
    };
    epi(accA, psA0, psA1, yA);
    epi(accB, psB0, psB1, yB);

    __syncthreads();
    float* lsf = reinterpret_cast<float*>(&smem[0][0]);   // [16][256]
    const int r = wave * 4 + g16;
    #pragma unroll
    for (int t = 0; t < 4; ++t) {
        lsf[r * 256 + 0 * 64 + t * 16 + c15] = psA0[t];
        lsf[r * 256 + 1 * 64 + t * 16 + c15] = psA1[t];
        lsf[r * 256 + 2 * 64 + t * 16 + c15] = psB0[t];
        lsf[r * 256 + 3 * 64 + t * 16 + c15] = psB1[t];
    }
    __syncthreads();
    const int tid = threadIdx.x;
    float s = 0.f;
    #pragma unroll
    for (int rr = 0; rr < 16; ++rr) s += lsf[rr * 256 + tid];
    part[(size_t)blockIdx.x * 256 + tid] = s;
}

// ---------- merged conv2 & conv4 (CIN=64 bf16, folded W, bf16 out) ----------
__global__ __launch_bounds__(256, 8)
void conv24_kernel(const unsigned short* __restrict__ x2, const int* __restrict__ nbr2,
                   const float* __restrict__ tv2, const unsigned short* __restrict__ Wb2,
                   unsigned short* __restrict__ y2,
                   const unsigned short* __restrict__ x4, const int* __restrict__ nbr4,
                   const float* __restrict__ tv4, const unsigned short* __restrict__ Wb4,
                   unsigned short* __restrict__ y4,
                   float* __restrict__ part,    // [tile][256]
                   int n_vox, int ntile)
{
    const int lane = threadIdx.x & 63;
    const int wave = threadIdx.x >> 6;
    __shared__ __align__(16) char smem[4][4352];   // hitbuf(2KB) / stage union
    char* my = smem[wave];
    const bool second = blockIdx.x >= ntile;
    const int tile = second ? blockIdx.x - ntile : blockIdx.x;
    const unsigned short* x = second ? x4 : x2;
    const int* nbr = second ? nbr4 : nbr2;
    const float* tvec = second ? tv4 : tv2;
    const unsigned short* Wb = second ? Wb4 : Wb2;
    unsigned short* yout = second ? y4 : y2;

    const int c15 = lane & 15, g16 = lane >> 4;
    const int j7 = lane & 7, kk = j7 + (j7 >= 4 ? 1 : 0), vv = lane >> 3;
    const int v16 = tile * 64 + wave * 16;

    const size_t r0 = (size_t)(v16 + vv) * 9 + kk;
    const size_t r1 = (size_t)(v16 + 8 + vv) * 9 + kk;
    int p0 = nbr[r0], p1 = nbr[r1];

    const unsigned short* xr = x + (size_t)(v16 + c15) * 64 + g16 * 8;
    bf16x8 a0 = *reinterpret_cast<const bf16x8*>(xr);
    bf16x8 a1 = *reinterpret_cast<const bf16x8*>(xr + 32);

    bf16x8 bwC[2][4];
    #pragma unroll
    for (int kt = 0; kt < 2; ++kt)
        #pragma unroll
        for (int t = 0; t < 4; ++t)
            bwC[kt][t] = *reinterpret_cast<const bf16x8*>(Wb + (size_t)(((4*2+kt)*4+t)*64 + lane) * 8);

    f32x4 acc[4];
    #pragma unroll
    for (int t = 0; t < 4; ++t) {
        float tC = tvec[4 * 64 + t * 16 + c15];
        f32x4 z = {tC, tC, tC, tC};
        acc[t] = z;
    }
    #pragma unroll
    for (int t = 0; t < 4; ++t) {
        acc[t] = __builtin_amdgcn_mfma_f32_16x16x32_bf16(a0, bwC[0][t], acc[t], 0, 0, 0);
        acc[t] = __builtin_amdgcn_mfma_f32_16x16x32_bf16(a1, bwC[1][t], acc[t], 0, 0, 0);
    }

    ull m0 = __ballot(p0 < n_vox), m1 = __ballot(p1 < n_vox);
    const int nh = __popcll(m0) + __popcll(m1);

    auto walksel = [&](ull M, int preg, int slot, int base, int& sel0, int& sel1) {
        while (M) {
            int b = __builtin_ctzll(M); M &= M - 1;
            int src = __shfl(preg, b);
            int rs = slot - base;
            sel0 = ((lane >> 3) == rs)     ? src : sel0;
            sel1 = ((lane >> 3) == rs - 8) ? src : sel1;
            ++slot;
        }
        return slot;
    };
    auto stage2 = [&](int s0, int s1) {
        uint4 q0 = *reinterpret_cast<const uint4*>((const char*)x + (size_t)s0*128 + (lane&7)*16);
        uint4 q1 = *reinterpret_cast<const uint4*>((const char*)x + (size_t)s1*128 + (lane&7)*16);
        reinterpret_cast<uint4*>(my)[lane]      = q0;
        reinterpret_cast<uint4*>(my)[64 + lane] = q1;
    };
    auto kloop = [&](bf16x8 h0, bf16x8 h1, int base) {
        const int pref = __popcll(m0);
        for (int tap = 0; tap < 8; ++tap) {
            ull TM = REP8 << tap;
            ull k0 = m0 & TM, k1 = m1 & TM;
            if (!(k0 | k1)) continue;
            int k = tap + (tap >= 4 ? 1 : 0);
            bf16x8 bk[2][4];
            #pragma unroll
            for (int kt = 0; kt < 2; ++kt)
                #pragma unroll
                for (int t = 0; t < 4; ++t)
                    bk[kt][t] = *reinterpret_cast<const bf16x8*>(Wb + (size_t)(((k*2+kt)*4+t)*64 + lane) * 8);
            float tvk[4];
            #pragma unroll
            for (int t = 0; t < 4; ++t) tvk[t] = tvec[k * 64 + t * 16 + c15];
            f32x4 ch[4];
            #pragma unroll
            for (int t = 0; t < 4; ++t) { f32x4 z = {0.f,0.f,0.f,0.f}; ch[t] = z; }
            #pragma unroll
            for (int t = 0; t < 4; ++t) {
                ch[t] = __builtin_amdgcn_mfma_f32_16x16x32_bf16(h0, bk[0][t], ch[t], 0, 0, 0);
                ch[t] = __builtin_amdgcn_mfma_f32_16x16x32_bf16(h1, bk[1][t], ch[t], 0, 0, 0);
            }
            auto inj = [&](ull M, ull msrc, int spref, int vbase) {
                while (M) {
                    int b = __builtin_ctzll(M); M &= M - 1;
                    int slot = spref + __popcll(msrc & ((1ull << b) - 1ull));
                    int rs = slot - base;
                    if (rs < 0 || rs >= 16) continue;
                    int vb = vbase + (b >> 3);
                    int srclane = ((rs >> 2) << 4) + c15;
                    int jj = rs & 3, gp = vb >> 2, jp = vb & 3;
                    float v0, v1, v2, v3;
                    switch (jj) {
                    case 0: v0=__shfl(ch[0][0],srclane); v1=__shfl(ch[1][0],srclane);
                            v2=__shfl(ch[2][0],srclane); v3=__shfl(ch[3][0],srclane); break;
                    case 1: v0=__shfl(ch[0][1],srclane); v1=__shfl(ch[1][1],srclane);
                            v2=__shfl(ch[2][1],srclane); v3=__shfl(ch[3][1],srclane); break;
                    case 2: v0=__shfl(ch[0][2],srclane); v1=__shfl(ch[1][2],srclane);
                            v2=__shfl(ch[2][2],srclane); v3=__shfl(ch[3][2],srclane); break;
                    default: v0=__shfl(ch[0][3],srclane); v1=__shfl(ch[1][3],srclane);
                             v2=__shfl(ch[2][3],srclane); v3=__shfl(ch[3][3],srclane); break;
                    }
                    bool mine = (g16 == gp);
                    float z0 = mine ? (v0 + tvk[0]) : 0.f, z1 = mine ? (v1 + tvk[1]) : 0.f;
                    float z2 = mine ? (v2 + tvk[2]) : 0.f, z3 = mine ? (v3 + tvk[3]) : 0.f;
                    switch (jp) {
                    case 0: acc[0][0]+=z0; acc[1][0]+=z1; acc[2][0]+=z2; acc[3][0]+=z3; break;
                    case 1: acc[0][1]+=z0; acc[1][1]+=z1; acc[2][1]+=z2; acc[3][1]+=z3; break;
                    case 2: acc[0][2]+=z0; acc[1][2]+=z1; acc[2][2]+=z2; acc[3][2]+=z3; break;
                    default: acc[0][3]+=z0; acc[1][3]+=z1; acc[2][3]+=z2; acc[3][3]+=z3; break;
                    }
                }
            };
            inj(k0, m0, 0, 0);
            inj(k1, m1, pref, 8);
        }
    };

    {
        int s0 = 0, s1 = 0;
        int c0 = walksel(m0, p0, 0, 0, s0, s1);
        walksel(m1, p1, c0, 0, s0, s1);
        stage2(s0, s1);
    }
    if (nh) {
        bf16x8 h0 = *reinterpret_cast<const bf16x8*>(my + c15 * 128 + g16 * 16);
        bf16x8 h1 = *reinterpret_cast<const bf16x8*>(my + c15 * 128 + 64 + g16 * 16);
        kloop(h0, h1, 0);
        for (int base = 16; base < nh; base += 16) {
            int s0 = 0, s1 = 0;
            int c0 = walksel(m0, p0, 0, base, s0, s1);
            walksel(m1, p1, c0, base, s0, s1);
            stage2(s0, s1);
            bf16x8 g0 = *reinterpret_cast<const bf16x8*>(my + c15 * 128 + g16 * 16);
            bf16x8 g1 = *reinterpret_cast<const bf16x8*>(my + c15 * 128 + 64 + g16 * 16);
            kloop(g0, g1, base);
        }
    }

    // epilogue (reuse smem as stage)
    float ps0[4] = {0,0,0,0}, ps1[4] = {0,0,0,0};
    float* stg = reinterpret_cast<float*>(my);
    #pragma unroll
    for (int t = 0; t < 4; ++t) {
        const int col = t * 16 + c15;
        #pragma unroll
        for (int j = 0; j < 4; ++j) {
            float v = acc[t][j];
            v = v > 0.f ? v : 0.01f * v;
            ps0[t] += v;
            ps1[t] = fmaf(v, v, ps1[t]);
            stg[(g16 * 4 + j) * 68 + col] = v;
        }
    }
    const int mm = lane >> 2, cc0 = (lane & 3) * 16;
    float4 q0 = *reinterpret_cast<float4*>(&stg[mm * 68 + cc0]);
    float4 q1 = *reinterpret_cast<float4*>(&stg[mm * 68 + cc0 + 4]);
    float4 q2 = *reinterpret_cast<float4*>(&stg[mm * 68 + cc0 + 8]);
    float4 q3 = *reinterpret_cast<float4*>(&stg[mm * 68 + cc0 + 12]);
    uint4 o0, o1;
    o0.x = pkbf(q0.x, q0.y); o0.y = pkbf(q0.z, q0.w);
    o0.z = pkbf(q1.x, q1.y); o0.w = pkbf(q1.z, q1.w);
    o1.x = pkbf(q2.x, q2.y); o1.y = pkbf(q2.z, q2.w);
    o1.z = pkbf(q3.x, q3.y); o1.w = pkbf(q3.z, q3.w);
    uint4* dst = reinterpret_cast<uint4*>(yout + (size_t)(v16 + mm) * 64 + cc0);
    dst[0] = o0; dst[1] = o1;

    __syncthreads();
    float* lsf = reinterpret_cast<float*>(&smem[0][0]);   // [16][128]
    const int r = wave * 4 + g16;
    #pragma unroll
    for (int t = 0; t < 4; ++t) {
        lsf[r * 128 + t * 16 + c15] = ps0[t];
        lsf[r * 128 + 64 + t * 16 + c15] = ps1[t];
    }
    __syncthreads();
    const int tid = threadIdx.x;
    if (tid < 128) {
        float s = 0.f;
        #pragma unroll
        for (int rr = 0; rr < 16; ++rr) s += lsf[rr * 128 + tid];
        part[(size_t)tile * 256 + (second ? 128 : 0) + tid] = s;
    }
}

// ---------- reduce partials + BN scale/shift (two layers per launch) ----------
__global__ void bnred_kernel(const float* __restrict__ part,   // [nblk][256]
                             const float* __restrict__ gA, const float* __restrict__ bA,
                             const float* __restrict__ gB, const float* __restrict__ bB,
                             float* __restrict__ scA, float* __restrict__ shA,
                             float* __restrict__ scB, float* __restrict__ shB,
                             float invN, int nblk)
{
    const int l = blockIdx.x >> 6, c = blockIdx.x & 63;   // grid 128
    const float* base = part + (size_t)(l * 2) * 64 + c;
    __shared__ float red[256][2];
    float s = 0.f, q = 0.f;
    for (int b = threadIdx.x; b < nblk; b += 256) {
        s += base[(size_t)b * 256];
        q += base[(size_t)b * 256 + 64];
    }
    red[threadIdx.x][0] = s; red[threadIdx.x][1] = q;
    __syncthreads();
    for (int off = 128; off; off >>= 1) {
        if (threadIdx.x < off) {
            red[threadIdx.x][0] += red[threadIdx.x + off][0];
            red[threadIdx.x][1] += red[threadIdx.x + off][1];
        }
        __syncthreads();
    }
    if (threadIdx.x == 0) {
        float m = red[0][0] * invN;
        float v = red[0][1] * invN - m * m;
        const float* g = l ? gB : gA;
        const float* bb = l ? bB : bA;
        float* sc = l ? scB : scA;
        float* sh = l ? shB : shA;
        float scale = g[c] / sqrtf(v + EPSF);
        sc[c] = scale;
        sh[c] = bb[c] - m * scale;
    }
}

// ---------- fold BN1/BN3 into W2/W4: tvec + bf16 B-frags for ALL 9 ks ----------
__global__ void foldpack_kernel(const float* __restrict__ W2, const float* __restrict__ W4,
                                const float* __restrict__ sc1, const float* __restrict__ sh1,
                                const float* __restrict__ sc3, const float* __restrict__ sh3,
                                float* __restrict__ t2, float* __restrict__ t4,
                                unsigned short* __restrict__ Wb2, unsigned short* __restrict__ Wb4)
{
    int i = blockIdx.x * 256 + threadIdx.x;
    if (i < 2 * 9 * 64) {
        const float* W = i < 9 * 64 ? W2 : W4;
        const float* shift = i < 9 * 64 ? sh1 : sh3;
        float* tv = i < 9 * 64 ? t2 : t4;
        int ii = i < 9 * 64 ? i : i - 9 * 64;
        int d = ii & 63, k = ii >> 6;
        float t = 0.f;
        for (int c = 0; c < 64; ++c)
            t = fmaf(shift[c], W[((size_t)k * 64 + c) * 64 + d], t);
        tv[ii] = t;
    } else {
        int p = i - 2 * 9 * 64;
        if (p >= 2 * 9 * 4096) return;
        const float* W = p < 9 * 4096 ? W2 : W4;
        const float* scale = p < 9 * 4096 ? sc1 : sc3;
        unsigned short* Wb = p < 9 * 4096 ? Wb2 : Wb4;
        int pp = p < 9 * 4096 ? p : p - 9 * 4096;
        int k = pp >> 12, rest = pp & 4095;
        int kt = rest >> 11, t = (rest >> 9) & 3, lane = (rest >> 3) & 63, j = rest & 7;
        int c = kt * 32 + (lane >> 4) * 8 + j;
        int d = t * 16 + (lane & 15);
        Wb[pp] = f2bf(scale[c] * W[((size_t)k * 64 + c) * 64 + d]);
    }
}

// ---------- final: out = BN2(y2) + BN4(y4), bf16 in, fp32 out ----------
__global__ void final_kernel(const unsigned short* __restrict__ y2,
                             const unsigned short* __restrict__ y4,
                             const float* __restrict__ sc2, const float* __restrict__ sh2,
                             const float* __restrict__ sc4, const float* __restrict__ sh4,
                             float* __restrict__ out, int n8)
{
    int i = blockIdx.x * 256 + threadIdx.x;
    if (i >= n8) return;
    const int c0 = (i & 7) * 8;
    uint4 aq = *reinterpret_cast<const uint4*>(y2 + (size_t)i * 8);
    uint4 bq = *reinterpret_cast<const uint4*>(y4 + (size_t)i * 8);
    float a[8], b[8];
    a[0] = __uint_as_float(aq.x << 16); a[1] = __uint_as_float(aq.x & 0xffff0000u);
    a[2] = __uint_as_float(aq.y << 16); a[3] = __uint_as_float(aq.y & 0xffff0000u);
    a[4] = __uint_as_float(aq.z << 16); a[5] = __uint_as_float(aq.z & 0xffff0000u);
    a[6] = __uint_as_float(aq.w << 16); a[7] = __uint_as_float(aq.w & 0xffff0000u);
    b[0] = __uint_as_float(bq.x << 16); b[1] = __uint_as_float(bq.x & 0xffff0000u);
    b[2] = __uint_as_float(bq.y << 16); b[3] = __uint_as_float(bq.y & 0xffff0000u);
    b[4] = __uint_as_float(bq.z << 16); b[5] = __uint_as_float(bq.z & 0xffff0000u);
    b[6] = __uint_as_float(bq.w << 16); b[7] = __uint_as_float(bq.w & 0xffff0000u);
    float r[8];
    #pragma unroll
    for (int j = 0; j < 8; ++j)
        r[j] = fmaf(a[j], sc2[c0 + j], sh2[c0 + j]) + fmaf(b[j], sc4[c0 + j], sh4[c0 + j]);
    float4 o0 = {r[0], r[1], r[2], r[3]};
    float4 o1 = {r[4], r[5], r[6], r[7]};
    float* po = out + (size_t)i * 8;
    *reinterpret_cast<float4*>(po) = o0;
    *reinterpret_cast<float4*>(po + 4) = o1;
}

extern "C" void kernel_launch(void* const* d_in, const int* in_sizes, int n_in,
                              void* d_out, int out_size, void* d_ws, size_t ws_size,
                              hipStream_t stream)
{
    const float* feats  = (const float*)d_in[0];
    const int*   nbr133 = (const int*)d_in[1];
    const int*   nbr313 = (const int*)d_in[2];
    const float* W1 = (const float*)d_in[3];
    const float* W2 = (const float*)d_in[4];
    const float* W3 = (const float*)d_in[5];
    const float* W4 = (const float*)d_in[6];
    const float* g0  = (const float*)d_in[7];
    const float* b0  = (const float*)d_in[8];
    const float* g02 = (const float*)d_in[9];
    const float* b02 = (const float*)d_in[10];
    const float* g1  = (const float*)d_in[11];
    const float* b1  = (const float*)d_in[12];
    const float* g2  = (const float*)d_in[13];
    const float* b2  = (const float*)d_in[14];

    const int N = in_sizes[0] / 32;
    const int ntile = N >> 6;                         // 3125 for N=200000

    char* w = (char*)d_ws;
    auto alloc = [&](size_t bytes) {
        char* p = w;
        w += (bytes + 255) & ~(size_t)255;
        return p;
    };
    unsigned short* y1 = (unsigned short*)alloc((size_t)N * 64 * 2);
    unsigned short* y3 = (unsigned short*)alloc((size_t)N * 64 * 2);
    unsigned short* y2 = (unsigned short*)alloc((size_t)N * 64 * 2);
    unsigned short* y4 = (unsigned short*)alloc((size_t)N * 64 * 2);
    float* t2 = (float*)alloc(9 * 64 * 4);
    float* t4 = (float*)alloc(9 * 64 * 4);
    unsigned short* Wb1 = (unsigned short*)alloc(9 * 4 * 64 * 8 * 2);
    unsigned short* Wb3 = (unsigned short*)alloc(9 * 4 * 64 * 8 * 2);
    unsigned short* Wb2 = (unsigned short*)alloc(9 * 2 * 4 * 64 * 8 * 2);
    unsigned short* Wb4 = (unsigned short*)alloc(9 * 2 * 4 * 64 * 8 * 2);
    float* part13 = (float*)alloc((size_t)ntile * 256 * 4);
    float* part24 = (float*)alloc((size_t)ntile * 256 * 4);
    float* scl = (float*)alloc(8 * 64 * 4);
    float *sc1 = scl,       *sh1 = scl + 64;
    float *sc3 = scl + 128, *sh3 = scl + 192;
    float *sc2 = scl + 256, *sh2 = scl + 320;
    float *sc4 = scl + 384, *sh4 = scl + 448;

    const float invN = 1.0f / (float)N;

    prep_kernel<<<(2 * 9 * 2048 + 255) / 256, 256, 0, stream>>>(W1, W3, Wb1, Wb3);

    conv13_kernel<<<ntile, 256, 0, stream>>>(feats, nbr133, nbr313, Wb1, Wb3,
                                             y1, y3, part13, N);
    bnred_kernel<<<128, 256, 0, stream>>>(part13, g0, b0, g1, b1,
                                          sc1, sh1, sc3, sh3, invN, ntile);
    foldpack_kernel<<<(2 * 9 * 64 + 2 * 9 * 4096 + 255) / 256, 256, 0, stream>>>(
        W2, W4, sc1, sh1, sc3, sh3, t2, t4, Wb2, Wb4);

    conv24_kernel<<<2 * ntile, 256, 0, stream>>>(y1, nbr313, t2, Wb2, y2,
                                                 y3, nbr133, t4, Wb4, y4,
                                                 part24, N, ntile);
    bnred_kernel<<<128, 256, 0, stream>>>(part24, g02, b02, g2, b2,
                                          sc2, sh2, sc4, sh4, invN, ntile);

    final_kernel<<<(N * 8 + 255) / 256, 256, 0, stream>>>(
        y2, y4, sc2, sh2, sc4, sh4, (float*)d_out, N * 8);
}

// Round 7
// 140.806 us; speedup vs baseline: 1.2915x; 1.2915x over previous
//
#include <hip/hip_runtime.h>
#include <hip/hip_bf16.h>

// ResContextBlock R7: R6 (native cvt_pk, switch-inject, LDS union) but with
// __launch_bounds__(256,4) -- R6's (256,8) forced VGPR=32 and spilled to
// scratch (FETCH 3x, WRITE 4x). 128-VGPR cap restores natural allocation.

typedef __attribute__((ext_vector_type(8))) short bf16x8;
typedef __attribute__((ext_vector_type(4))) float f32x4;
typedef unsigned long long ull;

#define EPSF 1e-5f
#define REP8 0x0101010101010101ull

__device__ __forceinline__ unsigned short f2bf(float f) {
    union { __hip_bfloat16 h; unsigned short u; } cv;
    cv.h = __float2bfloat16(f);   // RNE; compiler emits v_cvt_pk_bf16_f32
    return cv.u;
}
__device__ __forceinline__ unsigned pkbf(float lo, float hi) {
    return (unsigned)f2bf(lo) | ((unsigned)f2bf(hi) << 16);
}

// ---------- prep: pack W1,W3 -> bf16 B-frags for ALL 9 ks ----------
__global__ void prep_kernel(const float* __restrict__ W1, const float* __restrict__ W3,
                            unsigned short* __restrict__ Wb1, unsigned short* __restrict__ Wb3)
{
    int i = blockIdx.x * 256 + threadIdx.x;
    if (i >= 2 * 9 * 2048) return;
    const float* W = i < 9 * 2048 ? W1 : W3;
    unsigned short* Wb = i < 9 * 2048 ? Wb1 : Wb3;
    int pp = i < 9 * 2048 ? i : i - 9 * 2048;
    int k = pp >> 11, rest = pp & 2047;
    int t = (rest >> 9) & 3, lane = (rest >> 3) & 63, j = rest & 7;
    int c = (lane >> 4) * 8 + j;
    int d = t * 16 + (lane & 15);
    Wb[pp] = f2bf(W[(size_t)(k * 32 + c) * 64 + d]);
}

// ---------- fused conv1+conv3 (CIN=32 fp32 in, bf16 y out) ----------
__global__ __launch_bounds__(256, 4)
void conv13_kernel(const float* __restrict__ x,
                   const int* __restrict__ nbrA, const int* __restrict__ nbrB,
                   const unsigned short* __restrict__ WbA,
                   const unsigned short* __restrict__ WbB,
                   unsigned short* __restrict__ yA, unsigned short* __restrict__ yB,
                   float* __restrict__ part,    // [tile][256]
                   int n_vox)
{
    const int lane = threadIdx.x & 63;
    const int wave = threadIdx.x >> 6;
    // per-wave 4352B: hit staging (A rows @0, B rows @2048; 4KB) OR
    // epilogue stage ([16][68] floats = 4352B) -- disjoint lifetimes.
    __shared__ __align__(16) char smem[4][4352];
    char* my = smem[wave];
    const int c15 = lane & 15, g16 = lane >> 4;
    const int j7 = lane & 7, kk = j7 + (j7 >= 4 ? 1 : 0), vv = lane >> 3;
    const int v16 = blockIdx.x * 64 + wave * 16;

    // probes
    const size_t r0 = (size_t)(v16 + vv) * 9 + kk;
    const size_t r1 = (size_t)(v16 + 8 + vv) * 9 + kk;
    int pA0 = nbrA[r0], pA1 = nbrA[r1];
    int pB0 = nbrB[r0], pB1 = nbrB[r1];

    // dense A-frag (fp32 -> bf16)
    const float* xr = x + (size_t)(v16 + c15) * 32 + g16 * 8;
    float4 x0 = *reinterpret_cast<const float4*>(xr);
    float4 x1 = *reinterpret_cast<const float4*>(xr + 4);

    bf16x8 bA[4], bB[4];
    #pragma unroll
    for (int t = 0; t < 4; ++t) {
        bA[t] = *reinterpret_cast<const bf16x8*>(WbA + (size_t)((4*4+t)*64 + lane) * 8);
        bB[t] = *reinterpret_cast<const bf16x8*>(WbB + (size_t)((4*4+t)*64 + lane) * 8);
    }
    bf16x8 af;
    af[0]=(short)f2bf(x0.x); af[1]=(short)f2bf(x0.y); af[2]=(short)f2bf(x0.z); af[3]=(short)f2bf(x0.w);
    af[4]=(short)f2bf(x1.x); af[5]=(short)f2bf(x1.y); af[6]=(short)f2bf(x1.z); af[7]=(short)f2bf(x1.w);

    f32x4 accA[4], accB[4];
    #pragma unroll
    for (int t = 0; t < 4; ++t) { f32x4 z = {0.f,0.f,0.f,0.f}; accA[t] = z; accB[t] = z; }
    #pragma unroll
    for (int t = 0; t < 4; ++t) {
        accA[t] = __builtin_amdgcn_mfma_f32_16x16x32_bf16(af, bA[t], accA[t], 0, 0, 0);
        accB[t] = __builtin_amdgcn_mfma_f32_16x16x32_bf16(af, bB[t], accB[t], 0, 0, 0);
    }

    ull mA0 = __ballot(pA0 < n_vox), mA1 = __ballot(pA1 < n_vox);
    ull mB0 = __ballot(pB0 < n_vox), mB1 = __ballot(pB1 < n_vox);
    const int nhA = __popcll(mA0) + __popcll(mA1);
    const int nhB = __popcll(mB0) + __popcll(mB1);

    auto walksel = [&](ull M, int preg, int slot, int base, int& sel0, int& sel1) {
        while (M) {
            int b = __builtin_ctzll(M); M &= M - 1;
            int src = __shfl(preg, b);
            int rs = slot - base;
            sel0 = ((lane >> 3) == rs)     ? src : sel0;
            sel1 = ((lane >> 3) == rs - 8) ? src : sel1;
            ++slot;
        }
        return slot;
    };
    auto stage2 = [&](int s0, int s1, int off4) {
        uint4 q0 = *reinterpret_cast<const uint4*>((const char*)x + (size_t)s0*128 + (lane&7)*16);
        uint4 q1 = *reinterpret_cast<const uint4*>((const char*)x + (size_t)s1*128 + (lane&7)*16);
        reinterpret_cast<uint4*>(my)[off4 + lane]      = q0;
        reinterpret_cast<uint4*>(my)[off4 + 64 + lane] = q1;
    };
    auto loadfrag = [&](int hbyte) {
        const float* hf = reinterpret_cast<const float*>(my + hbyte + c15 * 128 + g16 * 32);
        float4 f0 = *reinterpret_cast<const float4*>(hf);
        float4 f1 = *reinterpret_cast<const float4*>(hf + 4);
        bf16x8 h;
        h[0]=(short)f2bf(f0.x); h[1]=(short)f2bf(f0.y); h[2]=(short)f2bf(f0.z); h[3]=(short)f2bf(f0.w);
        h[4]=(short)f2bf(f1.x); h[5]=(short)f2bf(f1.y); h[6]=(short)f2bf(f1.z); h[7]=(short)f2bf(f1.w);
        return h;
    };
    auto kloop = [&](ull m0, ull m1, bf16x8 h, const unsigned short* Wb,
                     f32x4* acc, int base) {
        const int pref = __popcll(m0);
        for (int tap = 0; tap < 8; ++tap) {
            ull TM = REP8 << tap;
            ull k0 = m0 & TM, k1 = m1 & TM;
            if (!(k0 | k1)) continue;
            int k = tap + (tap >= 4 ? 1 : 0);
            bf16x8 bk[4];
            #pragma unroll
            for (int t = 0; t < 4; ++t)
                bk[t] = *reinterpret_cast<const bf16x8*>(Wb + (size_t)((k*4+t)*64 + lane) * 8);
            f32x4 ch[4];
            #pragma unroll
            for (int t = 0; t < 4; ++t) { f32x4 z = {0.f,0.f,0.f,0.f}; ch[t] = z; }
            #pragma unroll
            for (int t = 0; t < 4; ++t)
                ch[t] = __builtin_amdgcn_mfma_f32_16x16x32_bf16(h, bk[t], ch[t], 0, 0, 0);
            auto inj = [&](ull M, ull msrc, int spref, int vbase) {
                while (M) {
                    int b = __builtin_ctzll(M); M &= M - 1;
                    int slot = spref + __popcll(msrc & ((1ull << b) - 1ull));
                    int rs = slot - base;
                    if (rs < 0 || rs >= 16) continue;
                    int vb = vbase + (b >> 3);
                    int srclane = ((rs >> 2) << 4) + c15;        // uniform group + lane col
                    int jj = rs & 3, gp = vb >> 2, jp = vb & 3;  // all SGPR-uniform
                    float v0, v1, v2, v3;
                    switch (jj) {
                    case 0: v0=__shfl(ch[0][0],srclane); v1=__shfl(ch[1][0],srclane);
                            v2=__shfl(ch[2][0],srclane); v3=__shfl(ch[3][0],srclane); break;
                    case 1: v0=__shfl(ch[0][1],srclane); v1=__shfl(ch[1][1],srclane);
                            v2=__shfl(ch[2][1],srclane); v3=__shfl(ch[3][1],srclane); break;
                    case 2: v0=__shfl(ch[0][2],srclane); v1=__shfl(ch[1][2],srclane);
                            v2=__shfl(ch[2][2],srclane); v3=__shfl(ch[3][2],srclane); break;
                    default: v0=__shfl(ch[0][3],srclane); v1=__shfl(ch[1][3],srclane);
                             v2=__shfl(ch[2][3],srclane); v3=__shfl(ch[3][3],srclane); break;
                    }
                    bool mine = (g16 == gp);
                    float z0 = mine ? v0 : 0.f, z1 = mine ? v1 : 0.f;
                    float z2 = mine ? v2 : 0.f, z3 = mine ? v3 : 0.f;
                    switch (jp) {
                    case 0: acc[0][0]+=z0; acc[1][0]+=z1; acc[2][0]+=z2; acc[3][0]+=z3; break;
                    case 1: acc[0][1]+=z0; acc[1][1]+=z1; acc[2][1]+=z2; acc[3][1]+=z3; break;
                    case 2: acc[0][2]+=z0; acc[1][2]+=z1; acc[2][2]+=z2; acc[3][2]+=z3; break;
                    default: acc[0][3]+=z0; acc[1][3]+=z1; acc[2][3]+=z2; acc[3][3]+=z3; break;
                    }
                }
            };
            inj(k0, m0, 0, 0);
            inj(k1, m1, pref, 8);
        }
    };

    // batch-0 staging for BOTH tables
    {
        int sA0=0, sA1=0, sB0=0, sB1=0;
        int cA = walksel(mA0, pA0, 0, 0, sA0, sA1);
        walksel(mA1, pA1, cA, 0, sA0, sA1);
        int cB = walksel(mB0, pB0, 0, 0, sB0, sB1);
        walksel(mB1, pB1, cB, 0, sB0, sB1);
        stage2(sA0, sA1, 0);
        stage2(sB0, sB1, 128);
    }
    if (nhA) {
        bf16x8 hA = loadfrag(0);
        kloop(mA0, mA1, hA, WbA, accA, 0);
        for (int base = 16; base < nhA; base += 16) {
            int s0=0, s1=0;
            int c0 = walksel(mA0, pA0, 0, base, s0, s1);
            walksel(mA1, pA1, c0, base, s0, s1);
            stage2(s0, s1, 0);
            bf16x8 h = loadfrag(0);
            kloop(mA0, mA1, h, WbA, accA, base);
        }
    }
    if (nhB) {
        bf16x8 hB = loadfrag(2048);
        kloop(mB0, mB1, hB, WbB, accB, 0);
        for (int base = 16; base < nhB; base += 16) {
            int s0=0, s1=0;
            int c0 = walksel(mB0, pB0, 0, base, s0, s1);
            walksel(mB1, pB1, c0, base, s0, s1);
            stage2(s0, s1, 128);
            bf16x8 h = loadfrag(2048);
            kloop(mB0, mB1, h, WbB, accB, base);
        }
    }

    // epilogue (hitbuf lifetime over; reuse smem as [16][68] stage)
    float psA0[4], psA1[4], psB0[4], psB1[4];
    #pragma unroll
    for (int t = 0; t < 4; ++t) { psA0[t]=0.f; psA1[t]=0.f; psB0[t]=0.f; psB1[t]=0.f; }

    auto epi = [&](f32x4* acc, float* ps0, float* ps1, unsigned short* yo) {
        float* stg = reinterpret_cast<float*>(my);
        #pragma unroll
        for (int t = 0; t < 4; ++t) {
            const int col = t * 16 + c15;
            #pragma unroll
            for (int j = 0; j < 4; ++j) {
                float v = acc[t][j];
                v = v > 0.f ? v : 0.01f * v;
                ps0[t] += v;
                ps1[t] = fmaf(v, v, ps1[t]);
                stg[(g16 * 4 + j) * 68 + col] = v;
            }
        }
        const int mm = lane >> 2, cc0 = (lane & 3) * 16;
        float4 q0 = *reinterpret_cast<float4*>(&stg[mm * 68 + cc0]);
        float4 q1 = *reinterpret_cast<float4*>(&stg[mm * 68 + cc0 + 4]);
        float4 q2 = *reinterpret_cast<float4*>(&stg[mm * 68 + cc0 + 8]);
        float4 q3 = *reinterpret_cast<float4*>(&stg[mm * 68 + cc0 + 12]);
        uint4 o0, o1;
        o0.x = pkbf(q0.x, q0.y); o0.y = pkbf(q0.z, q0.w);
        o0.z = pkbf(q1.x, q1.y); o0.w = pkbf(q1.z, q1.w);
        o1.x = pkbf(q2.x, q2.y); o1.y = pkbf(q2.z, q2.w);
        o1.z = pkbf(q3.x, q3.y); o1.w = pkbf(q3.z, q3.w);
        uint4* dst = reinterpret_cast<uint4*>(yo + (size_t)(v16 + mm) * 64 + cc0);
        dst[0] = o0; dst[1] = o1;
    };
    epi(accA, psA0, psA1, yA);
    epi(accB, psB0, psB1, yB);

    __syncthreads();
    float* lsf = reinterpret_cast<float*>(&smem[0][0]);   // [16][256]
    const int r = wave * 4 + g16;
    #pragma unroll
    for (int t = 0; t < 4; ++t) {
        lsf[r * 256 + 0 * 64 + t * 16 + c15] = psA0[t];
        lsf[r * 256 + 1 * 64 + t * 16 + c15] = psA1[t];
        lsf[r * 256 + 2 * 64 + t * 16 + c15] = psB0[t];
        lsf[r * 256 + 3 * 64 + t * 16 + c15] = psB1[t];
    }
    __syncthreads();
    const int tid = threadIdx.x;
    float s = 0.f;
    #pragma unroll
    for (int rr = 0; rr < 16; ++rr) s += lsf[rr * 256 + tid];
    part[(size_t)blockIdx.x * 256 + tid] = s;
}

// ---------- merged conv2 & conv4 (CIN=64 bf16, folded W, bf16 out) ----------
__global__ __launch_bounds__(256, 4)
void conv24_kernel(const unsigned short* __restrict__ x2, const int* __restrict__ nbr2,
                   const float* __restrict__ tv2, const unsigned short* __restrict__ Wb2,
                   unsigned short* __restrict__ y2,
                   const unsigned short* __restrict__ x4, const int* __restrict__ nbr4,
                   const float* __restrict__ tv4, const unsigned short* __restrict__ Wb4,
                   unsigned short* __restrict__ y4,
                   float* __restrict__ part,    // [tile][256]
                   int n_vox, int ntile)
{
    const int lane = threadIdx.x & 63;
    const int wave = threadIdx.x >> 6;
    __shared__ __align__(16) char smem[4][4352];   // hitbuf(2KB) / stage union
    char* my = smem[wave];
    const bool second = blockIdx.x >= ntile;
    const int tile = second ? blockIdx.x - ntile : blockIdx.x;
    const unsigned short* x = second ? x4 : x2;
    const int* nbr = second ? nbr4 : nbr2;
    const float* tvec = second ? tv4 : tv2;
    const unsigned short* Wb = second ? Wb4 : Wb2;
    unsigned short* yout = second ? y4 : y2;

    const int c15 = lane & 15, g16 = lane >> 4;
    const int j7 = lane & 7, kk = j7 + (j7 >= 4 ? 1 : 0), vv = lane >> 3;
    const int v16 = tile * 64 + wave * 16;

    const size_t r0 = (size_t)(v16 + vv) * 9 + kk;
    const size_t r1 = (size_t)(v16 + 8 + vv) * 9 + kk;
    int p0 = nbr[r0], p1 = nbr[r1];

    const unsigned short* xr = x + (size_t)(v16 + c15) * 64 + g16 * 8;
    bf16x8 a0 = *reinterpret_cast<const bf16x8*>(xr);
    bf16x8 a1 = *reinterpret_cast<const bf16x8*>(xr + 32);

    bf16x8 bwC[2][4];
    #pragma unroll
    for (int kt = 0; kt < 2; ++kt)
        #pragma unroll
        for (int t = 0; t < 4; ++t)
            bwC[kt][t] = *reinterpret_cast<const bf16x8*>(Wb + (size_t)(((4*2+kt)*4+t)*64 + lane) * 8);

    f32x4 acc[4];
    #pragma unroll
    for (int t = 0; t < 4; ++t) {
        float tC = tvec[4 * 64 + t * 16 + c15];
        f32x4 z = {tC, tC, tC, tC};
        acc[t] = z;
    }
    #pragma unroll
    for (int t = 0; t < 4; ++t) {
        acc[t] = __builtin_amdgcn_mfma_f32_16x16x32_bf16(a0, bwC[0][t], acc[t], 0, 0, 0);
        acc[t] = __builtin_amdgcn_mfma_f32_16x16x32_bf16(a1, bwC[1][t], acc[t], 0, 0, 0);
    }

    ull m0 = __ballot(p0 < n_vox), m1 = __ballot(p1 < n_vox);
    const int nh = __popcll(m0) + __popcll(m1);

    auto walksel = [&](ull M, int preg, int slot, int base, int& sel0, int& sel1) {
        while (M) {
            int b = __builtin_ctzll(M); M &= M - 1;
            int src = __shfl(preg, b);
            int rs = slot - base;
            sel0 = ((lane >> 3) == rs)     ? src : sel0;
            sel1 = ((lane >> 3) == rs - 8) ? src : sel1;
            ++slot;
        }
        return slot;
    };
    auto stage2 = [&](int s0, int s1) {
        uint4 q0 = *reinterpret_cast<const uint4*>((const char*)x + (size_t)s0*128 + (lane&7)*16);
        uint4 q1 = *reinterpret_cast<const uint4*>((const char*)x + (size_t)s1*128 + (lane&7)*16);
        reinterpret_cast<uint4*>(my)[lane]      = q0;
        reinterpret_cast<uint4*>(my)[64 + lane] = q1;
    };
    auto kloop = [&](bf16x8 h0, bf16x8 h1, int base) {
        const int pref = __popcll(m0);
        for (int tap = 0; tap < 8; ++tap) {
            ull TM = REP8 << tap;
            ull k0 = m0 & TM, k1 = m1 & TM;
            if (!(k0 | k1)) continue;
            int k = tap + (tap >= 4 ? 1 : 0);
            bf16x8 bk[2][4];
            #pragma unroll
            for (int kt = 0; kt < 2; ++kt)
                #pragma unroll
                for (int t = 0; t < 4; ++t)
                    bk[kt][t] = *reinterpret_cast<const bf16x8*>(Wb + (size_t)(((k*2+kt)*4+t)*64 + lane) * 8);
            float tvk[4];
            #pragma unroll
            for (int t = 0; t < 4; ++t) tvk[t] = tvec[k * 64 + t * 16 + c15];
            f32x4 ch[4];
            #pragma unroll
            for (int t = 0; t < 4; ++t) { f32x4 z = {0.f,0.f,0.f,0.f}; ch[t] = z; }
            #pragma unroll
            for (int t = 0; t < 4; ++t) {
                ch[t] = __builtin_amdgcn_mfma_f32_16x16x32_bf16(h0, bk[0][t], ch[t], 0, 0, 0);
                ch[t] = __builtin_amdgcn_mfma_f32_16x16x32_bf16(h1, bk[1][t], ch[t], 0, 0, 0);
            }
            auto inj = [&](ull M, ull msrc, int spref, int vbase) {
                while (M) {
                    int b = __builtin_ctzll(M); M &= M - 1;
                    int slot = spref + __popcll(msrc & ((1ull << b) - 1ull));
                    int rs = slot - base;
                    if (rs < 0 || rs >= 16) continue;
                    int vb = vbase + (b >> 3);
                    int srclane = ((rs >> 2) << 4) + c15;
                    int jj = rs & 3, gp = vb >> 2, jp = vb & 3;
                    float v0, v1, v2, v3;
                    switch (jj) {
                    case 0: v0=__shfl(ch[0][0],srclane); v1=__shfl(ch[1][0],srclane);
                            v2=__shfl(ch[2][0],srclane); v3=__shfl(ch[3][0],srclane); break;
                    case 1: v0=__shfl(ch[0][1],srclane); v1=__shfl(ch[1][1],srclane);
                            v2=__shfl(ch[2][1],srclane); v3=__shfl(ch[3][1],srclane); break;
                    case 2: v0=__shfl(ch[0][2],srclane); v1=__shfl(ch[1][2],srclane);
                            v2=__shfl(ch[2][2],srclane); v3=__shfl(ch[3][2],srclane); break;
                    default: v0=__shfl(ch[0][3],srclane); v1=__shfl(ch[1][3],srclane);
                             v2=__shfl(ch[2][3],srclane); v3=__shfl(ch[3][3],srclane); break;
                    }
                    bool mine = (g16 == gp);
                    float z0 = mine ? (v0 + tvk[0]) : 0.f, z1 = mine ? (v1 + tvk[1]) : 0.f;
                    float z2 = mine ? (v2 + tvk[2]) : 0.f, z3 = mine ? (v3 + tvk[3]) : 0.f;
                    switch (jp) {
                    case 0: acc[0][0]+=z0; acc[1][0]+=z1; acc[2][0]+=z2; acc[3][0]+=z3; break;
                    case 1: acc[0][1]+=z0; acc[1][1]+=z1; acc[2][1]+=z2; acc[3][1]+=z3; break;
                    case 2: acc[0][2]+=z0; acc[1][2]+=z1; acc[2][2]+=z2; acc[3][2]+=z3; break;
                    default: acc[0][3]+=z0; acc[1][3]+=z1; acc[2][3]+=z2; acc[3][3]+=z3; break;
                    }
                }
            };
            inj(k0, m0, 0, 0);
            inj(k1, m1, pref, 8);
        }
    };

    {
        int s0 = 0, s1 = 0;
        int c0 = walksel(m0, p0, 0, 0, s0, s1);
        walksel(m1, p1, c0, 0, s0, s1);
        stage2(s0, s1);
    }
    if (nh) {
        bf16x8 h0 = *reinterpret_cast<const bf16x8*>(my + c15 * 128 + g16 * 16);
        bf16x8 h1 = *reinterpret_cast<const bf16x8*>(my + c15 * 128 + 64 + g16 * 16);
        kloop(h0, h1, 0);
        for (int base = 16; base < nh; base += 16) {
            int s0 = 0, s1 = 0;
            int c0 = walksel(m0, p0, 0, base, s0, s1);
            walksel(m1, p1, c0, base, s0, s1);
            stage2(s0, s1);
            bf16x8 g0 = *reinterpret_cast<const bf16x8*>(my + c15 * 128 + g16 * 16);
            bf16x8 g1 = *reinterpret_cast<const bf16x8*>(my + c15 * 128 + 64 + g16 * 16);
            kloop(g0, g1, base);
        }
    }

    // epilogue (reuse smem as stage)
    float ps0[4] = {0,0,0,0}, ps1[4] = {0,0,0,0};
    float* stg = reinterpret_cast<float*>(my);
    #pragma unroll
    for (int t = 0; t < 4; ++t) {
        const int col = t * 16 + c15;
        #pragma unroll
        for (int j = 0; j < 4; ++j) {
            float v = acc[t][j];
            v = v > 0.f ? v : 0.01f * v;
            ps0[t] += v;
            ps1[t] = fmaf(v, v, ps1[t]);
            stg[(g16 * 4 + j) * 68 + col] = v;
        }
    }
    const int mm = lane >> 2, cc0 = (lane & 3) * 16;
    float4 q0 = *reinterpret_cast<float4*>(&stg[mm * 68 + cc0]);
    float4 q1 = *reinterpret_cast<float4*>(&stg[mm * 68 + cc0 + 4]);
    float4 q2 = *reinterpret_cast<float4*>(&stg[mm * 68 + cc0 + 8]);
    float4 q3 = *reinterpret_cast<float4*>(&stg[mm * 68 + cc0 + 12]);
    uint4 o0, o1;
    o0.x = pkbf(q0.x, q0.y); o0.y = pkbf(q0.z, q0.w);
    o0.z = pkbf(q1.x, q1.y); o0.w = pkbf(q1.z, q1.w);
    o1.x = pkbf(q2.x, q2.y); o1.y = pkbf(q2.z, q2.w);
    o1.z = pkbf(q3.x, q3.y); o1.w = pkbf(q3.z, q3.w);
    uint4* dst = reinterpret_cast<uint4*>(yout + (size_t)(v16 + mm) * 64 + cc0);
    dst[0] = o0; dst[1] = o1;

    __syncthreads();
    float* lsf = reinterpret_cast<float*>(&smem[0][0]);   // [16][128]
    const int r = wave * 4 + g16;
    #pragma unroll
    for (int t = 0; t < 4; ++t) {
        lsf[r * 128 + t * 16 + c15] = ps0[t];
        lsf[r * 128 + 64 + t * 16 + c15] = ps1[t];
    }
    __syncthreads();
    const int tid = threadIdx.x;
    if (tid < 128) {
        float s = 0.f;
        #pragma unroll
        for (int rr = 0; rr < 16; ++rr) s += lsf[rr * 128 + tid];
        part[(size_t)tile * 256 + (second ? 128 : 0) + tid] = s;
    }
}

// ---------- reduce partials + BN scale/shift (two layers per launch) ----------
__global__ void bnred_kernel(const float* __restrict__ part,   // [nblk][256]
                             const float* __restrict__ gA, const float* __restrict__ bA,
                             const float* __restrict__ gB, const float* __restrict__ bB,
                             float* __restrict__ scA, float* __restrict__ shA,
                             float* __restrict__ scB, float* __restrict__ shB,
                             float invN, int nblk)
{
    const int l = blockIdx.x >> 6, c = blockIdx.x & 63;   // grid 128
    const float* base = part + (size_t)(l * 2) * 64 + c;
    __shared__ float red[256][2];
    float s = 0.f, q = 0.f;
    for (int b = threadIdx.x; b < nblk; b += 256) {
        s += base[(size_t)b * 256];
        q += base[(size_t)b * 256 + 64];
    }
    red[threadIdx.x][0] = s; red[threadIdx.x][1] = q;
    __syncthreads();
    for (int off = 128; off; off >>= 1) {
        if (threadIdx.x < off) {
            red[threadIdx.x][0] += red[threadIdx.x + off][0];
            red[threadIdx.x][1] += red[threadIdx.x + off][1];
        }
        __syncthreads();
    }
    if (threadIdx.x == 0) {
        float m = red[0][0] * invN;
        float v = red[0][1] * invN - m * m;
        const float* g = l ? gB : gA;
        const float* bb = l ? bB : bA;
        float* sc = l ? scB : scA;
        float* sh = l ? shB : shA;
        float scale = g[c] / sqrtf(v + EPSF);
        sc[c] = scale;
        sh[c] = bb[c] - m * scale;
    }
}

// ---------- fold BN1/BN3 into W2/W4: tvec + bf16 B-frags for ALL 9 ks ----------
__global__ void foldpack_kernel(const float* __restrict__ W2, const float* __restrict__ W4,
                                const float* __restrict__ sc1, const float* __restrict__ sh1,
                                const float* __restrict__ sc3, const float* __restrict__ sh3,
                                float* __restrict__ t2, float* __restrict__ t4,
                                unsigned short* __restrict__ Wb2, unsigned short* __restrict__ Wb4)
{
    int i = blockIdx.x * 256 + threadIdx.x;
    if (i < 2 * 9 * 64) {
        const float* W = i < 9 * 64 ? W2 : W4;
        const float* shift = i < 9 * 64 ? sh1 : sh3;
        float* tv = i < 9 * 64 ? t2 : t4;
        int ii = i < 9 * 64 ? i : i - 9 * 64;
        int d = ii & 63, k = ii >> 6;
        float t = 0.f;
        for (int c = 0; c < 64; ++c)
            t = fmaf(shift[c], W[((size_t)k * 64 + c) * 64 + d], t);
        tv[ii] = t;
    } else {
        int p = i - 2 * 9 * 64;
        if (p >= 2 * 9 * 4096) return;
        const float* W = p < 9 * 4096 ? W2 : W4;
        const float* scale = p < 9 * 4096 ? sc1 : sc3;
        unsigned short* Wb = p < 9 * 4096 ? Wb2 : Wb4;
        int pp = p < 9 * 4096 ? p : p - 9 * 4096;
        int k = pp >> 12, rest = pp & 4095;
        int kt = rest >> 11, t = (rest >> 9) & 3, lane = (rest >> 3) & 63, j = rest & 7;
        int c = kt * 32 + (lane >> 4) * 8 + j;
        int d = t * 16 + (lane & 15);
        Wb[pp] = f2bf(scale[c] * W[((size_t)k * 64 + c) * 64 + d]);
    }
}

// ---------- final: out = BN2(y2) + BN4(y4), bf16 in, fp32 out ----------
__global__ void final_kernel(const unsigned short* __restrict__ y2,
                             const unsigned short* __restrict__ y4,
                             const float* __restrict__ sc2, const float* __restrict__ sh2,
                             const float* __restrict__ sc4, const float* __restrict__ sh4,
                             float* __restrict__ out, int n8)
{
    int i = blockIdx.x * 256 + threadIdx.x;
    if (i >= n8) return;
    const int c0 = (i & 7) * 8;
    uint4 aq = *reinterpret_cast<const uint4*>(y2 + (size_t)i * 8);
    uint4 bq = *reinterpret_cast<const uint4*>(y4 + (size_t)i * 8);
    float a[8], b[8];
    a[0] = __uint_as_float(aq.x << 16); a[1] = __uint_as_float(aq.x & 0xffff0000u);
    a[2] = __uint_as_float(aq.y << 16); a[3] = __uint_as_float(aq.y & 0xffff0000u);
    a[4] = __uint_as_float(aq.z << 16); a[5] = __uint_as_float(aq.z & 0xffff0000u);
    a[6] = __uint_as_float(aq.w << 16); a[7] = __uint_as_float(aq.w & 0xffff0000u);
    b[0] = __uint_as_float(bq.x << 16); b[1] = __uint_as_float(bq.x & 0xffff0000u);
    b[2] = __uint_as_float(bq.y << 16); b[3] = __uint_as_float(bq.y & 0xffff0000u);
    b[4] = __uint_as_float(bq.z << 16); b[5] = __uint_as_float(bq.z & 0xffff0000u);
    b[6] = __uint_as_float(bq.w << 16); b[7] = __uint_as_float(bq.w & 0xffff0000u);
    float r[8];
    #pragma unroll
    for (int j = 0; j < 8; ++j)
        r[j] = fmaf(a[j], sc2[c0 + j], sh2[c0 + j]) + fmaf(b[j], sc4[c0 + j], sh4[c0 + j]);
    float4 o0 = {r[0], r[1], r[2], r[3]};
    float4 o1 = {r[4], r[5], r[6], r[7]};
    float* po = out + (size_t)i * 8;
    *reinterpret_cast<float4*>(po) = o0;
    *reinterpret_cast<float4*>(po + 4) = o1;
}

extern "C" void kernel_launch(void* const* d_in, const int* in_sizes, int n_in,
                              void* d_out, int out_size, void* d_ws, size_t ws_size,
                              hipStream_t stream)
{
    const float* feats  = (const float*)d_in[0];
    const int*   nbr133 = (const int*)d_in[1];
    const int*   nbr313 = (const int*)d_in[2];
    const float* W1 = (const float*)d_in[3];
    const float* W2 = (const float*)d_in[4];
    const float* W3 = (const float*)d_in[5];
    const float* W4 = (const float*)d_in[6];
    const float* g0  = (const float*)d_in[7];
    const float* b0  = (const float*)d_in[8];
    const float* g02 = (const float*)d_in[9];
    const float* b02 = (const float*)d_in[10];
    const float* g1  = (const float*)d_in[11];
    const float* b1  = (const float*)d_in[12];
    const float* g2  = (const float*)d_in[13];
    const float* b2  = (const float*)d_in[14];

    const int N = in_sizes[0] / 32;
    const int ntile = N >> 6;                         // 3125 for N=200000

    char* w = (char*)d_ws;
    auto alloc = [&](size_t bytes) {
        char* p = w;
        w += (bytes + 255) & ~(size_t)255;
        return p;
    };
    unsigned short* y1 = (unsigned short*)alloc((size_t)N * 64 * 2);
    unsigned short* y3 = (unsigned short*)alloc((size_t)N * 64 * 2);
    unsigned short* y2 = (unsigned short*)alloc((size_t)N * 64 * 2);
    unsigned short* y4 = (unsigned short*)alloc((size_t)N * 64 * 2);
    float* t2 = (float*)alloc(9 * 64 * 4);
    float* t4 = (float*)alloc(9 * 64 * 4);
    unsigned short* Wb1 = (unsigned short*)alloc(9 * 4 * 64 * 8 * 2);
    unsigned short* Wb3 = (unsigned short*)alloc(9 * 4 * 64 * 8 * 2);
    unsigned short* Wb2 = (unsigned short*)alloc(9 * 2 * 4 * 64 * 8 * 2);
    unsigned short* Wb4 = (unsigned short*)alloc(9 * 2 * 4 * 64 * 8 * 2);
    float* part13 = (float*)alloc((size_t)ntile * 256 * 4);
    float* part24 = (float*)alloc((size_t)ntile * 256 * 4);
    float* scl = (float*)alloc(8 * 64 * 4);
    float *sc1 = scl,       *sh1 = scl + 64;
    float *sc3 = scl + 128, *sh3 = scl + 192;
    float *sc2 = scl + 256, *sh2 = scl + 320;
    float *sc4 = scl + 384, *sh4 = scl + 448;

    const float invN = 1.0f / (float)N;

    prep_kernel<<<(2 * 9 * 2048 + 255) / 256, 256, 0, stream>>>(W1, W3, Wb1, Wb3);

    conv13_kernel<<<ntile, 256, 0, stream>>>(feats, nbr133, nbr313, Wb1, Wb3,
                                             y1, y3, part13, N);
    bnred_kernel<<<128, 256, 0, stream>>>(part13, g0, b0, g1, b1,
                                          sc1, sh1, sc3, sh3, invN, ntile);
    foldpack_kernel<<<(2 * 9 * 64 + 2 * 9 * 4096 + 255) / 256, 256, 0, stream>>>(
        W2, W4, sc1, sh1, sc3, sh3, t2, t4, Wb2, Wb4);

    conv24_kernel<<<2 * ntile, 256, 0, stream>>>(y1, nbr313, t2, Wb2, y2,
                                                 y3, nbr133, t4, Wb4, y4,
                                                 part24, N, ntile);
    bnred_kernel<<<128, 256, 0, stream>>>(part24, g02, b02, g2, b2,
                                          sc2, sh2, sc4, sh4, invN, ntile);

    final_kernel<<<(N * 8 + 255) / 256, 256, 0, stream>>>(
        y2, y4, sc2, sh2, sc4, sh4, (float*)d_out, N * 8);
}

// Round 8
// 130.897 us; speedup vs baseline: 1.3893x; 1.0757x over previous
//
#include <hip/hip_runtime.h>
#include <hip/hip_bf16.h>

// ResContextBlock R8: R7 minus the hit-staging LDS round-trip. Off-center hit
// rows are gathered DIRECTLY from global in A-frag layout (lane reads 16B of
// row sel[c15] at granule g16) -- removes stage2/loadfrag LDS ops, their
// 16-way bank conflicts, and shortens the probe->MFMA dependent chain.

typedef __attribute__((ext_vector_type(8))) short bf16x8;
typedef __attribute__((ext_vector_type(4))) float f32x4;
typedef unsigned long long ull;

#define EPSF 1e-5f
#define REP8 0x0101010101010101ull

__device__ __forceinline__ unsigned short f2bf(float f) {
    union { __hip_bfloat16 h; unsigned short u; } cv;
    cv.h = __float2bfloat16(f);   // RNE; compiler emits v_cvt_pk_bf16_f32
    return cv.u;
}
__device__ __forceinline__ unsigned pkbf(float lo, float hi) {
    return (unsigned)f2bf(lo) | ((unsigned)f2bf(hi) << 16);
}

// ---------- prep: pack W1,W3 -> bf16 B-frags for ALL 9 ks ----------
__global__ void prep_kernel(const float* __restrict__ W1, const float* __restrict__ W3,
                            unsigned short* __restrict__ Wb1, unsigned short* __restrict__ Wb3)
{
    int i = blockIdx.x * 256 + threadIdx.x;
    if (i >= 2 * 9 * 2048) return;
    const float* W = i < 9 * 2048 ? W1 : W3;
    unsigned short* Wb = i < 9 * 2048 ? Wb1 : Wb3;
    int pp = i < 9 * 2048 ? i : i - 9 * 2048;
    int k = pp >> 11, rest = pp & 2047;
    int t = (rest >> 9) & 3, lane = (rest >> 3) & 63, j = rest & 7;
    int c = (lane >> 4) * 8 + j;
    int d = t * 16 + (lane & 15);
    Wb[pp] = f2bf(W[(size_t)(k * 32 + c) * 64 + d]);
}

// ---------- fused conv1+conv3 (CIN=32 fp32 in, bf16 y out) ----------
__global__ __launch_bounds__(256, 4)
void conv13_kernel(const float* __restrict__ x,
                   const int* __restrict__ nbrA, const int* __restrict__ nbrB,
                   const unsigned short* __restrict__ WbA,
                   const unsigned short* __restrict__ WbB,
                   unsigned short* __restrict__ yA, unsigned short* __restrict__ yB,
                   float* __restrict__ part,    // [tile][256]
                   int n_vox)
{
    const int lane = threadIdx.x & 63;
    const int wave = threadIdx.x >> 6;
    __shared__ __align__(16) char smem[4][4352];   // epilogue stage only
    char* my = smem[wave];
    const int c15 = lane & 15, g16 = lane >> 4;
    const int j7 = lane & 7, kk = j7 + (j7 >= 4 ? 1 : 0), vv = lane >> 3;
    const int v16 = blockIdx.x * 64 + wave * 16;

    // probes
    const size_t r0 = (size_t)(v16 + vv) * 9 + kk;
    const size_t r1 = (size_t)(v16 + 8 + vv) * 9 + kk;
    int pA0 = nbrA[r0], pA1 = nbrA[r1];
    int pB0 = nbrB[r0], pB1 = nbrB[r1];

    // dense A-frag (fp32 -> bf16)
    const float* xr = x + (size_t)(v16 + c15) * 32 + g16 * 8;
    float4 x0 = *reinterpret_cast<const float4*>(xr);
    float4 x1 = *reinterpret_cast<const float4*>(xr + 4);

    bf16x8 bA[4], bB[4];
    #pragma unroll
    for (int t = 0; t < 4; ++t) {
        bA[t] = *reinterpret_cast<const bf16x8*>(WbA + (size_t)((4*4+t)*64 + lane) * 8);
        bB[t] = *reinterpret_cast<const bf16x8*>(WbB + (size_t)((4*4+t)*64 + lane) * 8);
    }
    bf16x8 af;
    af[0]=(short)f2bf(x0.x); af[1]=(short)f2bf(x0.y); af[2]=(short)f2bf(x0.z); af[3]=(short)f2bf(x0.w);
    af[4]=(short)f2bf(x1.x); af[5]=(short)f2bf(x1.y); af[6]=(short)f2bf(x1.z); af[7]=(short)f2bf(x1.w);

    f32x4 accA[4], accB[4];
    #pragma unroll
    for (int t = 0; t < 4; ++t) { f32x4 z = {0.f,0.f,0.f,0.f}; accA[t] = z; accB[t] = z; }
    #pragma unroll
    for (int t = 0; t < 4; ++t) {
        accA[t] = __builtin_amdgcn_mfma_f32_16x16x32_bf16(af, bA[t], accA[t], 0, 0, 0);
        accB[t] = __builtin_amdgcn_mfma_f32_16x16x32_bf16(af, bB[t], accB[t], 0, 0, 0);
    }

    ull mA0 = __ballot(pA0 < n_vox), mA1 = __ballot(pA1 < n_vox);
    ull mB0 = __ballot(pB0 < n_vox), mB1 = __ballot(pB1 < n_vox);
    const int nhA = __popcll(mA0) + __popcll(mA1);
    const int nhB = __popcll(mB0) + __popcll(mB1);

    // broadcast src row for slot rs in [base,base+16): lane keyed on c15
    auto walksel = [&](ull M, int preg, int slot, int base, int& sel) {
        while (M) {
            int b = __builtin_ctzll(M); M &= M - 1;
            int src = __shfl(preg, b);
            sel = (c15 == slot - base) ? src : sel;
            ++slot;
        }
        return slot;
    };
    // direct global gather of hit A-frag: lane reads row sel, floats g16*8..+8
    auto gatherfrag = [&](int sel) {
        const float* hr = x + (size_t)sel * 32 + g16 * 8;
        float4 f0 = *reinterpret_cast<const float4*>(hr);
        float4 f1 = *reinterpret_cast<const float4*>(hr + 4);
        bf16x8 h;
        h[0]=(short)f2bf(f0.x); h[1]=(short)f2bf(f0.y); h[2]=(short)f2bf(f0.z); h[3]=(short)f2bf(f0.w);
        h[4]=(short)f2bf(f1.x); h[5]=(short)f2bf(f1.y); h[6]=(short)f2bf(f1.z); h[7]=(short)f2bf(f1.w);
        return h;
    };
    auto kloop = [&](ull m0, ull m1, bf16x8 h, const unsigned short* Wb,
                     f32x4* acc, int base) {
        const int pref = __popcll(m0);
        for (int tap = 0; tap < 8; ++tap) {
            ull TM = REP8 << tap;
            ull k0 = m0 & TM, k1 = m1 & TM;
            if (!(k0 | k1)) continue;
            int k = tap + (tap >= 4 ? 1 : 0);
            bf16x8 bk[4];
            #pragma unroll
            for (int t = 0; t < 4; ++t)
                bk[t] = *reinterpret_cast<const bf16x8*>(Wb + (size_t)((k*4+t)*64 + lane) * 8);
            f32x4 ch[4];
            #pragma unroll
            for (int t = 0; t < 4; ++t) { f32x4 z = {0.f,0.f,0.f,0.f}; ch[t] = z; }
            #pragma unroll
            for (int t = 0; t < 4; ++t)
                ch[t] = __builtin_amdgcn_mfma_f32_16x16x32_bf16(h, bk[t], ch[t], 0, 0, 0);
            auto inj = [&](ull M, ull msrc, int spref, int vbase) {
                while (M) {
                    int b = __builtin_ctzll(M); M &= M - 1;
                    int slot = spref + __popcll(msrc & ((1ull << b) - 1ull));
                    int rs = slot - base;
                    if (rs < 0 || rs >= 16) continue;
                    int vb = vbase + (b >> 3);
                    int srclane = ((rs >> 2) << 4) + c15;        // uniform group + lane col
                    int jj = rs & 3, gp = vb >> 2, jp = vb & 3;  // all SGPR-uniform
                    float v0, v1, v2, v3;
                    switch (jj) {
                    case 0: v0=__shfl(ch[0][0],srclane); v1=__shfl(ch[1][0],srclane);
                            v2=__shfl(ch[2][0],srclane); v3=__shfl(ch[3][0],srclane); break;
                    case 1: v0=__shfl(ch[0][1],srclane); v1=__shfl(ch[1][1],srclane);
                            v2=__shfl(ch[2][1],srclane); v3=__shfl(ch[3][1],srclane); break;
                    case 2: v0=__shfl(ch[0][2],srclane); v1=__shfl(ch[1][2],srclane);
                            v2=__shfl(ch[2][2],srclane); v3=__shfl(ch[3][2],srclane); break;
                    default: v0=__shfl(ch[0][3],srclane); v1=__shfl(ch[1][3],srclane);
                             v2=__shfl(ch[2][3],srclane); v3=__shfl(ch[3][3],srclane); break;
                    }
                    bool mine = (g16 == gp);
                    float z0 = mine ? v0 : 0.f, z1 = mine ? v1 : 0.f;
                    float z2 = mine ? v2 : 0.f, z3 = mine ? v3 : 0.f;
                    switch (jp) {
                    case 0: acc[0][0]+=z0; acc[1][0]+=z1; acc[2][0]+=z2; acc[3][0]+=z3; break;
                    case 1: acc[0][1]+=z0; acc[1][1]+=z1; acc[2][1]+=z2; acc[3][1]+=z3; break;
                    case 2: acc[0][2]+=z0; acc[1][2]+=z1; acc[2][2]+=z2; acc[3][2]+=z3; break;
                    default: acc[0][3]+=z0; acc[1][3]+=z1; acc[2][3]+=z2; acc[3][3]+=z3; break;
                    }
                }
            };
            inj(k0, m0, 0, 0);
            inj(k1, m1, pref, 8);
        }
    };

    // batch 0 for both tables: walksel + gather issued together (ILP)
    if (nhA | nhB) {
        int selA = 0, selB = 0;
        int cA = walksel(mA0, pA0, 0, 0, selA);
        walksel(mA1, pA1, cA, 0, selA);
        int cB = walksel(mB0, pB0, 0, 0, selB);
        walksel(mB1, pB1, cB, 0, selB);
        bf16x8 hA = gatherfrag(selA);
        bf16x8 hB = gatherfrag(selB);
        if (nhA) kloop(mA0, mA1, hA, WbA, accA, 0);
        if (nhB) kloop(mB0, mB1, hB, WbB, accB, 0);
        for (int base = 16; base < nhA; base += 16) {
            int s = 0;
            int c0 = walksel(mA0, pA0, 0, base, s);
            walksel(mA1, pA1, c0, base, s);
            kloop(mA0, mA1, gatherfrag(s), WbA, accA, base);
        }
        for (int base = 16; base < nhB; base += 16) {
            int s = 0;
            int c0 = walksel(mB0, pB0, 0, base, s);
            walksel(mB1, pB1, c0, base, s);
            kloop(mB0, mB1, gatherfrag(s), WbB, accB, base);
        }
    }

    // epilogue: lrelu, stats, pack bf16, store (LDS transpose)
    float psA0[4], psA1[4], psB0[4], psB1[4];
    #pragma unroll
    for (int t = 0; t < 4; ++t) { psA0[t]=0.f; psA1[t]=0.f; psB0[t]=0.f; psB1[t]=0.f; }

    auto epi = [&](f32x4* acc, float* ps0, float* ps1, unsigned short* yo) {
        float* stg = reinterpret_cast<float*>(my);
        #pragma unroll
        for (int t = 0; t < 4; ++t) {
            const int col = t * 16 + c15;
            #pragma unroll
            for (int j = 0; j < 4; ++j) {
                float v = acc[t][j];
                v = v > 0.f ? v : 0.01f * v;
                ps0[t] += v;
                ps1[t] = fmaf(v, v, ps1[t]);
                stg[(g16 * 4 + j) * 68 + col] = v;
            }
        }
        const int mm = lane >> 2, cc0 = (lane & 3) * 16;
        float4 q0 = *reinterpret_cast<float4*>(&stg[mm * 68 + cc0]);
        float4 q1 = *reinterpret_cast<float4*>(&stg[mm * 68 + cc0 + 4]);
        float4 q2 = *reinterpret_cast<float4*>(&stg[mm * 68 + cc0 + 8]);
        float4 q3 = *reinterpret_cast<float4*>(&stg[mm * 68 + cc0 + 12]);
        uint4 o0, o1;
        o0.x = pkbf(q0.x, q0.y); o0.y = pkbf(q0.z, q0.w);
        o0.z = pkbf(q1.x, q1.y); o0.w = pkbf(q1.z, q1.w);
        o1.x = pkbf(q2.x, q2.y); o1.y = pkbf(q2.z, q2.w);
        o1.z = pkbf(q3.x, q3.y); o1.w = pkbf(q3.z, q3.w);
        uint4* dst = reinterpret_cast<uint4*>(yo + (size_t)(v16 + mm) * 64 + cc0);
        dst[0] = o0; dst[1] = o1;
    };
    epi(accA, psA0, psA1, yA);
    epi(accB, psB0, psB1, yB);

    __syncthreads();
    float* lsf = reinterpret_cast<float*>(&smem[0][0]);   // [16][256]
    const int r = wave * 4 + g16;
    #pragma unroll
    for (int t = 0; t < 4; ++t) {
        lsf[r * 256 + 0 * 64 + t * 16 + c15] = psA0[t];
        lsf[r * 256 + 1 * 64 + t * 16 + c15] = psA1[t];
        lsf[r * 256 + 2 * 64 + t * 16 + c15] = psB0[t];
        lsf[r * 256 + 3 * 64 + t * 16 + c15] = psB1[t];
    }
    __syncthreads();
    const int tid = threadIdx.x;
    float s = 0.f;
    #pragma unroll
    for (int rr = 0; rr < 16; ++rr) s += lsf[rr * 256 + tid];
    part[(size_t)blockIdx.x * 256 + tid] = s;
}

// ---------- merged conv2 & conv4 (CIN=64 bf16, folded W, bf16 out) ----------
__global__ __launch_bounds__(256, 4)
void conv24_kernel(const unsigned short* __restrict__ x2, const int* __restrict__ nbr2,
                   const float* __restrict__ tv2, const unsigned short* __restrict__ Wb2,
                   unsigned short* __restrict__ y2,
                   const unsigned short* __restrict__ x4, const int* __restrict__ nbr4,
                   const float* __restrict__ tv4, const unsigned short* __restrict__ Wb4,
                   unsigned short* __restrict__ y4,
                   float* __restrict__ part,    // [tile][256]
                   int n_vox, int ntile)
{
    const int lane = threadIdx.x & 63;
    const int wave = threadIdx.x >> 6;
    __shared__ __align__(16) char smem[4][4352];   // epilogue stage only
    char* my = smem[wave];
    const bool second = blockIdx.x >= ntile;
    const int tile = second ? blockIdx.x - ntile : blockIdx.x;
    const unsigned short* x = second ? x4 : x2;
    const int* nbr = second ? nbr4 : nbr2;
    const float* tvec = second ? tv4 : tv2;
    const unsigned short* Wb = second ? Wb4 : Wb2;
    unsigned short* yout = second ? y4 : y2;

    const int c15 = lane & 15, g16 = lane >> 4;
    const int j7 = lane & 7, kk = j7 + (j7 >= 4 ? 1 : 0), vv = lane >> 3;
    const int v16 = tile * 64 + wave * 16;

    const size_t r0 = (size_t)(v16 + vv) * 9 + kk;
    const size_t r1 = (size_t)(v16 + 8 + vv) * 9 + kk;
    int p0 = nbr[r0], p1 = nbr[r1];

    const unsigned short* xr = x + (size_t)(v16 + c15) * 64 + g16 * 8;
    bf16x8 a0 = *reinterpret_cast<const bf16x8*>(xr);
    bf16x8 a1 = *reinterpret_cast<const bf16x8*>(xr + 32);

    bf16x8 bwC[2][4];
    #pragma unroll
    for (int kt = 0; kt < 2; ++kt)
        #pragma unroll
        for (int t = 0; t < 4; ++t)
            bwC[kt][t] = *reinterpret_cast<const bf16x8*>(Wb + (size_t)(((4*2+kt)*4+t)*64 + lane) * 8);

    f32x4 acc[4];
    #pragma unroll
    for (int t = 0; t < 4; ++t) {
        float tC = tvec[4 * 64 + t * 16 + c15];
        f32x4 z = {tC, tC, tC, tC};
        acc[t] = z;
    }
    #pragma unroll
    for (int t = 0; t < 4; ++t) {
        acc[t] = __builtin_amdgcn_mfma_f32_16x16x32_bf16(a0, bwC[0][t], acc[t], 0, 0, 0);
        acc[t] = __builtin_amdgcn_mfma_f32_16x16x32_bf16(a1, bwC[1][t], acc[t], 0, 0, 0);
    }

    ull m0 = __ballot(p0 < n_vox), m1 = __ballot(p1 < n_vox);
    const int nh = __popcll(m0) + __popcll(m1);

    auto walksel = [&](ull M, int preg, int slot, int base, int& sel) {
        while (M) {
            int b = __builtin_ctzll(M); M &= M - 1;
            int src = __shfl(preg, b);
            sel = (c15 == slot - base) ? src : sel;
            ++slot;
        }
        return slot;
    };
    auto kloop = [&](bf16x8 h0, bf16x8 h1, int base) {
        const int pref = __popcll(m0);
        for (int tap = 0; tap < 8; ++tap) {
            ull TM = REP8 << tap;
            ull k0 = m0 & TM, k1 = m1 & TM;
            if (!(k0 | k1)) continue;
            int k = tap + (tap >= 4 ? 1 : 0);
            bf16x8 bk[2][4];
            #pragma unroll
            for (int kt = 0; kt < 2; ++kt)
                #pragma unroll
                for (int t = 0; t < 4; ++t)
                    bk[kt][t] = *reinterpret_cast<const bf16x8*>(Wb + (size_t)(((k*2+kt)*4+t)*64 + lane) * 8);
            float tvk[4];
            #pragma unroll
            for (int t = 0; t < 4; ++t) tvk[t] = tvec[k * 64 + t * 16 + c15];
            f32x4 ch[4];
            #pragma unroll
            for (int t = 0; t < 4; ++t) { f32x4 z = {0.f,0.f,0.f,0.f}; ch[t] = z; }
            #pragma unroll
            for (int t = 0; t < 4; ++t) {
                ch[t] = __builtin_amdgcn_mfma_f32_16x16x32_bf16(h0, bk[0][t], ch[t], 0, 0, 0);
                ch[t] = __builtin_amdgcn_mfma_f32_16x16x32_bf16(h1, bk[1][t], ch[t], 0, 0, 0);
            }
            auto inj = [&](ull M, ull msrc, int spref, int vbase) {
                while (M) {
                    int b = __builtin_ctzll(M); M &= M - 1;
                    int slot = spref + __popcll(msrc & ((1ull << b) - 1ull));
                    int rs = slot - base;
                    if (rs < 0 || rs >= 16) continue;
                    int vb = vbase + (b >> 3);
                    int srclane = ((rs >> 2) << 4) + c15;
                    int jj = rs & 3, gp = vb >> 2, jp = vb & 3;
                    float v0, v1, v2, v3;
                    switch (jj) {
                    case 0: v0=__shfl(ch[0][0],srclane); v1=__shfl(ch[1][0],srclane);
                            v2=__shfl(ch[2][0],srclane); v3=__shfl(ch[3][0],srclane); break;
                    case 1: v0=__shfl(ch[0][1],srclane); v1=__shfl(ch[1][1],srclane);
                            v2=__shfl(ch[2][1],srclane); v3=__shfl(ch[3][1],srclane); break;
                    case 2: v0=__shfl(ch[0][2],srclane); v1=__shfl(ch[1][2],srclane);
                            v2=__shfl(ch[2][2],srclane); v3=__shfl(ch[3][2],srclane); break;
                    default: v0=__shfl(ch[0][3],srclane); v1=__shfl(ch[1][3],srclane);
                             v2=__shfl(ch[2][3],srclane); v3=__shfl(ch[3][3],srclane); break;
                    }
                    bool mine = (g16 == gp);
                    float z0 = mine ? (v0 + tvk[0]) : 0.f, z1 = mine ? (v1 + tvk[1]) : 0.f;
                    float z2 = mine ? (v2 + tvk[2]) : 0.f, z3 = mine ? (v3 + tvk[3]) : 0.f;
                    switch (jp) {
                    case 0: acc[0][0]+=z0; acc[1][0]+=z1; acc[2][0]+=z2; acc[3][0]+=z3; break;
                    case 1: acc[0][1]+=z0; acc[1][1]+=z1; acc[2][1]+=z2; acc[3][1]+=z3; break;
                    case 2: acc[0][2]+=z0; acc[1][2]+=z1; acc[2][2]+=z2; acc[3][2]+=z3; break;
                    default: acc[0][3]+=z0; acc[1][3]+=z1; acc[2][3]+=z2; acc[3][3]+=z3; break;
                    }
                }
            };
            inj(k0, m0, 0, 0);
            inj(k1, m1, pref, 8);
        }
    };

    for (int base = 0; base < nh; base += 16) {
        int sel = 0;
        int c0 = walksel(m0, p0, 0, base, sel);
        walksel(m1, p1, c0, base, sel);
        const unsigned short* hr = x + (size_t)sel * 64 + g16 * 8;
        bf16x8 h0 = *reinterpret_cast<const bf16x8*>(hr);
        bf16x8 h1 = *reinterpret_cast<const bf16x8*>(hr + 32);
        kloop(h0, h1, base);
    }

    // epilogue
    float ps0[4] = {0,0,0,0}, ps1[4] = {0,0,0,0};
    float* stg = reinterpret_cast<float*>(my);
    #pragma unroll
    for (int t = 0; t < 4; ++t) {
        const int col = t * 16 + c15;
        #pragma unroll
        for (int j = 0; j < 4; ++j) {
            float v = acc[t][j];
            v = v > 0.f ? v : 0.01f * v;
            ps0[t] += v;
            ps1[t] = fmaf(v, v, ps1[t]);
            stg[(g16 * 4 + j) * 68 + col] = v;
        }
    }
    const int mm = lane >> 2, cc0 = (lane & 3) * 16;
    float4 q0 = *reinterpret_cast<float4*>(&stg[mm * 68 + cc0]);
    float4 q1 = *reinterpret_cast<float4*>(&stg[mm * 68 + cc0 + 4]);
    float4 q2 = *reinterpret_cast<float4*>(&stg[mm * 68 + cc0 + 8]);
    float4 q3 = *reinterpret_cast<float4*>(&stg[mm * 68 + cc0 + 12]);
    uint4 o0, o1;
    o0.x = pkbf(q0.x, q0.y); o0.y = pkbf(q0.z, q0.w);
    o0.z = pkbf(q1.x, q1.y); o0.w = pkbf(q1.z, q1.w);
    o1.x = pkbf(q2.x, q2.y); o1.y = pkbf(q2.z, q2.w);
    o1.z = pkbf(q3.x, q3.y); o1.w = pkbf(q3.z, q3.w);
    uint4* dst = reinterpret_cast<uint4*>(yout + (size_t)(v16 + mm) * 64 + cc0);
    dst[0] = o0; dst[1] = o1;

    __syncthreads();
    float* lsf = reinterpret_cast<float*>(&smem[0][0]);   // [16][128]
    const int r = wave * 4 + g16;
    #pragma unroll
    for (int t = 0; t < 4; ++t) {
        lsf[r * 128 + t * 16 + c15] = ps0[t];
        lsf[r * 128 + 64 + t * 16 + c15] = ps1[t];
    }
    __syncthreads();
    const int tid = threadIdx.x;
    if (tid < 128) {
        float s = 0.f;
        #pragma unroll
        for (int rr = 0; rr < 16; ++rr) s += lsf[rr * 128 + tid];
        part[(size_t)tile * 256 + (second ? 128 : 0) + tid] = s;
    }
}

// ---------- reduce partials + BN scale/shift (two layers per launch) ----------
__global__ void bnred_kernel(const float* __restrict__ part,   // [nblk][256]
                             const float* __restrict__ gA, const float* __restrict__ bA,
                             const float* __restrict__ gB, const float* __restrict__ bB,
                             float* __restrict__ scA, float* __restrict__ shA,
                             float* __restrict__ scB, float* __restrict__ shB,
                             float invN, int nblk)
{
    const int l = blockIdx.x >> 6, c = blockIdx.x & 63;   // grid 128
    const float* base = part + (size_t)(l * 2) * 64 + c;
    __shared__ float red[256][2];
    float s = 0.f, q = 0.f;
    for (int b = threadIdx.x; b < nblk; b += 256) {
        s += base[(size_t)b * 256];
        q += base[(size_t)b * 256 + 64];
    }
    red[threadIdx.x][0] = s; red[threadIdx.x][1] = q;
    __syncthreads();
    for (int off = 128; off; off >>= 1) {
        if (threadIdx.x < off) {
            red[threadIdx.x][0] += red[threadIdx.x + off][0];
            red[threadIdx.x][1] += red[threadIdx.x + off][1];
        }
        __syncthreads();
    }
    if (threadIdx.x == 0) {
        float m = red[0][0] * invN;
        float v = red[0][1] * invN - m * m;
        const float* g = l ? gB : gA;
        const float* bb = l ? bB : bA;
        float* sc = l ? scB : scA;
        float* sh = l ? shB : shA;
        float scale = g[c] / sqrtf(v + EPSF);
        sc[c] = scale;
        sh[c] = bb[c] - m * scale;
    }
}

// ---------- fold BN1/BN3 into W2/W4: tvec + bf16 B-frags for ALL 9 ks ----------
__global__ void foldpack_kernel(const float* __restrict__ W2, const float* __restrict__ W4,
                                const float* __restrict__ sc1, const float* __restrict__ sh1,
                                const float* __restrict__ sc3, const float* __restrict__ sh3,
                                float* __restrict__ t2, float* __restrict__ t4,
                                unsigned short* __restrict__ Wb2, unsigned short* __restrict__ Wb4)
{
    int i = blockIdx.x * 256 + threadIdx.x;
    if (i < 2 * 9 * 64) {
        const float* W = i < 9 * 64 ? W2 : W4;
        const float* shift = i < 9 * 64 ? sh1 : sh3;
        float* tv = i < 9 * 64 ? t2 : t4;
        int ii = i < 9 * 64 ? i : i - 9 * 64;
        int d = ii & 63, k = ii >> 6;
        float t = 0.f;
        for (int c = 0; c < 64; ++c)
            t = fmaf(shift[c], W[((size_t)k * 64 + c) * 64 + d], t);
        tv[ii] = t;
    } else {
        int p = i - 2 * 9 * 64;
        if (p >= 2 * 9 * 4096) return;
        const float* W = p < 9 * 4096 ? W2 : W4;
        const float* scale = p < 9 * 4096 ? sc1 : sc3;
        unsigned short* Wb = p < 9 * 4096 ? Wb2 : Wb4;
        int pp = p < 9 * 4096 ? p : p - 9 * 4096;
        int k = pp >> 12, rest = pp & 4095;
        int kt = rest >> 11, t = (rest >> 9) & 3, lane = (rest >> 3) & 63, j = rest & 7;
        int c = kt * 32 + (lane >> 4) * 8 + j;
        int d = t * 16 + (lane & 15);
        Wb[pp] = f2bf(scale[c] * W[((size_t)k * 64 + c) * 64 + d]);
    }
}

// ---------- final: out = BN2(y2) + BN4(y4), bf16 in, fp32 out ----------
__global__ void final_kernel(const unsigned short* __restrict__ y2,
                             const unsigned short* __restrict__ y4,
                             const float* __restrict__ sc2, const float* __restrict__ sh2,
                             const float* __restrict__ sc4, const float* __restrict__ sh4,
                             float* __restrict__ out, int n8)
{
    int i = blockIdx.x * 256 + threadIdx.x;
    if (i >= n8) return;
    const int c0 = (i & 7) * 8;
    uint4 aq = *reinterpret_cast<const uint4*>(y2 + (size_t)i * 8);
    uint4 bq = *reinterpret_cast<const uint4*>(y4 + (size_t)i * 8);
    float a[8], b[8];
    a[0] = __uint_as_float(aq.x << 16); a[1] = __uint_as_float(aq.x & 0xffff0000u);
    a[2] = __uint_as_float(aq.y << 16); a[3] = __uint_as_float(aq.y & 0xffff0000u);
    a[4] = __uint_as_float(aq.z << 16); a[5] = __uint_as_float(aq.z & 0xffff0000u);
    a[6] = __uint_as_float(aq.w << 16); a[7] = __uint_as_float(aq.w & 0xffff0000u);
    b[0] = __uint_as_float(bq.x << 16); b[1] = __uint_as_float(bq.x & 0xffff0000u);
    b[2] = __uint_as_float(bq.y << 16); b[3] = __uint_as_float(bq.y & 0xffff0000u);
    b[4] = __uint_as_float(bq.z << 16); b[5] = __uint_as_float(bq.z & 0xffff0000u);
    b[6] = __uint_as_float(bq.w << 16); b[7] = __uint_as_float(bq.w & 0xffff0000u);
    float r[8];
    #pragma unroll
    for (int j = 0; j < 8; ++j)
        r[j] = fmaf(a[j], sc2[c0 + j], sh2[c0 + j]) + fmaf(b[j], sc4[c0 + j], sh4[c0 + j]);
    float4 o0 = {r[0], r[1], r[2], r[3]};
    float4 o1 = {r[4], r[5], r[6], r[7]};
    float* po = out + (size_t)i * 8;
    *reinterpret_cast<float4*>(po) = o0;
    *reinterpret_cast<float4*>(po + 4) = o1;
}

extern "C" void kernel_launch(void* const* d_in, const int* in_sizes, int n_in,
                              void* d_out, int out_size, void* d_ws, size_t ws_size,
                              hipStream_t stream)
{
    const float* feats  = (const float*)d_in[0];
    const int*   nbr133 = (const int*)d_in[1];
    const int*   nbr313 = (const int*)d_in[2];
    const float* W1 = (const float*)d_in[3];
    const float* W2 = (const float*)d_in[4];
    const float* W3 = (const float*)d_in[5];
    const float* W4 = (const float*)d_in[6];
    const float* g0  = (const float*)d_in[7];
    const float* b0  = (const float*)d_in[8];
    const float* g02 = (const float*)d_in[9];
    const float* b02 = (const float*)d_in[10];
    const float* g1  = (const float*)d_in[11];
    const float* b1  = (const float*)d_in[12];
    const float* g2  = (const float*)d_in[13];
    const float* b2  = (const float*)d_in[14];

    const int N = in_sizes[0] / 32;
    const int ntile = N >> 6;                         // 3125 for N=200000

    char* w = (char*)d_ws;
    auto alloc = [&](size_t bytes) {
        char* p = w;
        w += (bytes + 255) & ~(size_t)255;
        return p;
    };
    unsigned short* y1 = (unsigned short*)alloc((size_t)N * 64 * 2);
    unsigned short* y3 = (unsigned short*)alloc((size_t)N * 64 * 2);
    unsigned short* y2 = (unsigned short*)alloc((size_t)N * 64 * 2);
    unsigned short* y4 = (unsigned short*)alloc((size_t)N * 64 * 2);
    float* t2 = (float*)alloc(9 * 64 * 4);
    float* t4 = (float*)alloc(9 * 64 * 4);
    unsigned short* Wb1 = (unsigned short*)alloc(9 * 4 * 64 * 8 * 2);
    unsigned short* Wb3 = (unsigned short*)alloc(9 * 4 * 64 * 8 * 2);
    unsigned short* Wb2 = (unsigned short*)alloc(9 * 2 * 4 * 64 * 8 * 2);
    unsigned short* Wb4 = (unsigned short*)alloc(9 * 2 * 4 * 64 * 8 * 2);
    float* part13 = (float*)alloc((size_t)ntile * 256 * 4);
    float* part24 = (float*)alloc((size_t)ntile * 256 * 4);
    float* scl = (float*)alloc(8 * 64 * 4);
    float *sc1 = scl,       *sh1 = scl + 64;
    float *sc3 = scl + 128, *sh3 = scl + 192;
    float *sc2 = scl + 256, *sh2 = scl + 320;
    float *sc4 = scl + 384, *sh4 = scl + 448;

    const float invN = 1.0f / (float)N;

    prep_kernel<<<(2 * 9 * 2048 + 255) / 256, 256, 0, stream>>>(W1, W3, Wb1, Wb3);

    conv13_kernel<<<ntile, 256, 0, stream>>>(feats, nbr133, nbr313, Wb1, Wb3,
                                             y1, y3, part13, N);
    bnred_kernel<<<128, 256, 0, stream>>>(part13, g0, b0, g1, b1,
                                          sc1, sh1, sc3, sh3, invN, ntile);
    foldpack_kernel<<<(2 * 9 * 64 + 2 * 9 * 4096 + 255) / 256, 256, 0, stream>>>(
        W2, W4, sc1, sh1, sc3, sh3, t2, t4, Wb2, Wb4);

    conv24_kernel<<<2 * ntile, 256, 0, stream>>>(y1, nbr313, t2, Wb2, y2,
                                                 y3, nbr133, t4, Wb4, y4,
                                                 part24, N, ntile);
    bnred_kernel<<<128, 256, 0, stream>>>(part24, g02, b02, g2, b2,
                                          sc2, sh2, sc4, sh4, invN, ntile);

    final_kernel<<<(N * 8 + 255) / 256, 256, 0, stream>>>(
        y2, y4, sc2, sh2, sc4, sh4, (float*)d_out, N * 8);
}

// Round 9
// 130.791 us; speedup vs baseline: 1.3904x; 1.0008x over previous
//
#include <hip/hip_runtime.h>
#include <hip/hip_bf16.h>

// ResContextBlock R9: R8 + tile-paired conv24 -- each block processes TWO
// 64-voxel tiles of the same conv (shared weights/tvec, two independent
// memory chains per wave for latency hiding). Partials: [nb2][256].

typedef __attribute__((ext_vector_type(8))) short bf16x8;
typedef __attribute__((ext_vector_type(4))) float f32x4;
typedef unsigned long long ull;

#define EPSF 1e-5f
#define REP8 0x0101010101010101ull

__device__ __forceinline__ unsigned short f2bf(float f) {
    union { __hip_bfloat16 h; unsigned short u; } cv;
    cv.h = __float2bfloat16(f);   // RNE; compiler emits v_cvt_pk_bf16_f32
    return cv.u;
}
__device__ __forceinline__ unsigned pkbf(float lo, float hi) {
    return (unsigned)f2bf(lo) | ((unsigned)f2bf(hi) << 16);
}

// ---------- prep: pack W1,W3 -> bf16 B-frags for ALL 9 ks ----------
__global__ void prep_kernel(const float* __restrict__ W1, const float* __restrict__ W3,
                            unsigned short* __restrict__ Wb1, unsigned short* __restrict__ Wb3)
{
    int i = blockIdx.x * 256 + threadIdx.x;
    if (i >= 2 * 9 * 2048) return;
    const float* W = i < 9 * 2048 ? W1 : W3;
    unsigned short* Wb = i < 9 * 2048 ? Wb1 : Wb3;
    int pp = i < 9 * 2048 ? i : i - 9 * 2048;
    int k = pp >> 11, rest = pp & 2047;
    int t = (rest >> 9) & 3, lane = (rest >> 3) & 63, j = rest & 7;
    int c = (lane >> 4) * 8 + j;
    int d = t * 16 + (lane & 15);
    Wb[pp] = f2bf(W[(size_t)(k * 32 + c) * 64 + d]);
}

// ---------- fused conv1+conv3 (CIN=32 fp32 in, bf16 y out) ----------
__global__ __launch_bounds__(256, 4)
void conv13_kernel(const float* __restrict__ x,
                   const int* __restrict__ nbrA, const int* __restrict__ nbrB,
                   const unsigned short* __restrict__ WbA,
                   const unsigned short* __restrict__ WbB,
                   unsigned short* __restrict__ yA, unsigned short* __restrict__ yB,
                   float* __restrict__ part,    // [tile][256]
                   int n_vox)
{
    const int lane = threadIdx.x & 63;
    const int wave = threadIdx.x >> 6;
    __shared__ __align__(16) char smem[4][4352];   // epilogue stage only
    char* my = smem[wave];
    const int c15 = lane & 15, g16 = lane >> 4;
    const int j7 = lane & 7, kk = j7 + (j7 >= 4 ? 1 : 0), vv = lane >> 3;
    const int v16 = blockIdx.x * 64 + wave * 16;

    // probes
    const size_t r0 = (size_t)(v16 + vv) * 9 + kk;
    const size_t r1 = (size_t)(v16 + 8 + vv) * 9 + kk;
    int pA0 = nbrA[r0], pA1 = nbrA[r1];
    int pB0 = nbrB[r0], pB1 = nbrB[r1];

    // dense A-frag (fp32 -> bf16)
    const float* xr = x + (size_t)(v16 + c15) * 32 + g16 * 8;
    float4 x0 = *reinterpret_cast<const float4*>(xr);
    float4 x1 = *reinterpret_cast<const float4*>(xr + 4);

    bf16x8 bA[4], bB[4];
    #pragma unroll
    for (int t = 0; t < 4; ++t) {
        bA[t] = *reinterpret_cast<const bf16x8*>(WbA + (size_t)((4*4+t)*64 + lane) * 8);
        bB[t] = *reinterpret_cast<const bf16x8*>(WbB + (size_t)((4*4+t)*64 + lane) * 8);
    }
    bf16x8 af;
    af[0]=(short)f2bf(x0.x); af[1]=(short)f2bf(x0.y); af[2]=(short)f2bf(x0.z); af[3]=(short)f2bf(x0.w);
    af[4]=(short)f2bf(x1.x); af[5]=(short)f2bf(x1.y); af[6]=(short)f2bf(x1.z); af[7]=(short)f2bf(x1.w);

    f32x4 accA[4], accB[4];
    #pragma unroll
    for (int t = 0; t < 4; ++t) { f32x4 z = {0.f,0.f,0.f,0.f}; accA[t] = z; accB[t] = z; }
    #pragma unroll
    for (int t = 0; t < 4; ++t) {
        accA[t] = __builtin_amdgcn_mfma_f32_16x16x32_bf16(af, bA[t], accA[t], 0, 0, 0);
        accB[t] = __builtin_amdgcn_mfma_f32_16x16x32_bf16(af, bB[t], accB[t], 0, 0, 0);
    }

    ull mA0 = __ballot(pA0 < n_vox), mA1 = __ballot(pA1 < n_vox);
    ull mB0 = __ballot(pB0 < n_vox), mB1 = __ballot(pB1 < n_vox);
    const int nhA = __popcll(mA0) + __popcll(mA1);
    const int nhB = __popcll(mB0) + __popcll(mB1);

    auto walksel = [&](ull M, int preg, int slot, int base, int& sel) {
        while (M) {
            int b = __builtin_ctzll(M); M &= M - 1;
            int src = __shfl(preg, b);
            sel = (c15 == slot - base) ? src : sel;
            ++slot;
        }
        return slot;
    };
    auto gatherfrag = [&](int sel) {
        const float* hr = x + (size_t)sel * 32 + g16 * 8;
        float4 f0 = *reinterpret_cast<const float4*>(hr);
        float4 f1 = *reinterpret_cast<const float4*>(hr + 4);
        bf16x8 h;
        h[0]=(short)f2bf(f0.x); h[1]=(short)f2bf(f0.y); h[2]=(short)f2bf(f0.z); h[3]=(short)f2bf(f0.w);
        h[4]=(short)f2bf(f1.x); h[5]=(short)f2bf(f1.y); h[6]=(short)f2bf(f1.z); h[7]=(short)f2bf(f1.w);
        return h;
    };
    auto kloop = [&](ull m0, ull m1, bf16x8 h, const unsigned short* Wb,
                     f32x4* acc, int base) {
        const int pref = __popcll(m0);
        for (int tap = 0; tap < 8; ++tap) {
            ull TM = REP8 << tap;
            ull k0 = m0 & TM, k1 = m1 & TM;
            if (!(k0 | k1)) continue;
            int k = tap + (tap >= 4 ? 1 : 0);
            bf16x8 bk[4];
            #pragma unroll
            for (int t = 0; t < 4; ++t)
                bk[t] = *reinterpret_cast<const bf16x8*>(Wb + (size_t)((k*4+t)*64 + lane) * 8);
            f32x4 ch[4];
            #pragma unroll
            for (int t = 0; t < 4; ++t) { f32x4 z = {0.f,0.f,0.f,0.f}; ch[t] = z; }
            #pragma unroll
            for (int t = 0; t < 4; ++t)
                ch[t] = __builtin_amdgcn_mfma_f32_16x16x32_bf16(h, bk[t], ch[t], 0, 0, 0);
            auto inj = [&](ull M, ull msrc, int spref, int vbase) {
                while (M) {
                    int b = __builtin_ctzll(M); M &= M - 1;
                    int slot = spref + __popcll(msrc & ((1ull << b) - 1ull));
                    int rs = slot - base;
                    if (rs < 0 || rs >= 16) continue;
                    int vb = vbase + (b >> 3);
                    int srclane = ((rs >> 2) << 4) + c15;
                    int jj = rs & 3, gp = vb >> 2, jp = vb & 3;
                    float v0, v1, v2, v3;
                    switch (jj) {
                    case 0: v0=__shfl(ch[0][0],srclane); v1=__shfl(ch[1][0],srclane);
                            v2=__shfl(ch[2][0],srclane); v3=__shfl(ch[3][0],srclane); break;
                    case 1: v0=__shfl(ch[0][1],srclane); v1=__shfl(ch[1][1],srclane);
                            v2=__shfl(ch[2][1],srclane); v3=__shfl(ch[3][1],srclane); break;
                    case 2: v0=__shfl(ch[0][2],srclane); v1=__shfl(ch[1][2],srclane);
                            v2=__shfl(ch[2][2],srclane); v3=__shfl(ch[3][2],srclane); break;
                    default: v0=__shfl(ch[0][3],srclane); v1=__shfl(ch[1][3],srclane);
                             v2=__shfl(ch[2][3],srclane); v3=__shfl(ch[3][3],srclane); break;
                    }
                    bool mine = (g16 == gp);
                    float z0 = mine ? v0 : 0.f, z1 = mine ? v1 : 0.f;
                    float z2 = mine ? v2 : 0.f, z3 = mine ? v3 : 0.f;
                    switch (jp) {
                    case 0: acc[0][0]+=z0; acc[1][0]+=z1; acc[2][0]+=z2; acc[3][0]+=z3; break;
                    case 1: acc[0][1]+=z0; acc[1][1]+=z1; acc[2][1]+=z2; acc[3][1]+=z3; break;
                    case 2: acc[0][2]+=z0; acc[1][2]+=z1; acc[2][2]+=z2; acc[3][2]+=z3; break;
                    default: acc[0][3]+=z0; acc[1][3]+=z1; acc[2][3]+=z2; acc[3][3]+=z3; break;
                    }
                }
            };
            inj(k0, m0, 0, 0);
            inj(k1, m1, pref, 8);
        }
    };

    if (nhA | nhB) {
        int selA = 0, selB = 0;
        int cA = walksel(mA0, pA0, 0, 0, selA);
        walksel(mA1, pA1, cA, 0, selA);
        int cB = walksel(mB0, pB0, 0, 0, selB);
        walksel(mB1, pB1, cB, 0, selB);
        bf16x8 hA = gatherfrag(selA);
        bf16x8 hB = gatherfrag(selB);
        if (nhA) kloop(mA0, mA1, hA, WbA, accA, 0);
        if (nhB) kloop(mB0, mB1, hB, WbB, accB, 0);
        for (int base = 16; base < nhA; base += 16) {
            int s = 0;
            int c0 = walksel(mA0, pA0, 0, base, s);
            walksel(mA1, pA1, c0, base, s);
            kloop(mA0, mA1, gatherfrag(s), WbA, accA, base);
        }
        for (int base = 16; base < nhB; base += 16) {
            int s = 0;
            int c0 = walksel(mB0, pB0, 0, base, s);
            walksel(mB1, pB1, c0, base, s);
            kloop(mB0, mB1, gatherfrag(s), WbB, accB, base);
        }
    }

    // epilogue
    float psA0[4], psA1[4], psB0[4], psB1[4];
    #pragma unroll
    for (int t = 0; t < 4; ++t) { psA0[t]=0.f; psA1[t]=0.f; psB0[t]=0.f; psB1[t]=0.f; }

    auto epi = [&](f32x4* acc, float* ps0, float* ps1, unsigned short* yo) {
        float* stg = reinterpret_cast<float*>(my);
        #pragma unroll
        for (int t = 0; t < 4; ++t) {
            const int col = t * 16 + c15;
            #pragma unroll
            for (int j = 0; j < 4; ++j) {
                float v = acc[t][j];
                v = v > 0.f ? v : 0.01f * v;
                ps0[t] += v;
                ps1[t] = fmaf(v, v, ps1[t]);
                stg[(g16 * 4 + j) * 68 + col] = v;
            }
        }
        const int mm = lane >> 2, cc0 = (lane & 3) * 16;
        float4 q0 = *reinterpret_cast<float4*>(&stg[mm * 68 + cc0]);
        float4 q1 = *reinterpret_cast<float4*>(&stg[mm * 68 + cc0 + 4]);
        float4 q2 = *reinterpret_cast<float4*>(&stg[mm * 68 + cc0 + 8]);
        float4 q3 = *reinterpret_cast<float4*>(&stg[mm * 68 + cc0 + 12]);
        uint4 o0, o1;
        o0.x = pkbf(q0.x, q0.y); o0.y = pkbf(q0.z, q0.w);
        o0.z = pkbf(q1.x, q1.y); o0.w = pkbf(q1.z, q1.w);
        o1.x = pkbf(q2.x, q2.y); o1.y = pkbf(q2.z, q2.w);
        o1.z = pkbf(q3.x, q3.y); o1.w = pkbf(q3.z, q3.w);
        uint4* dst = reinterpret_cast<uint4*>(yo + (size_t)(v16 + mm) * 64 + cc0);
        dst[0] = o0; dst[1] = o1;
    };
    epi(accA, psA0, psA1, yA);
    epi(accB, psB0, psB1, yB);

    __syncthreads();
    float* lsf = reinterpret_cast<float*>(&smem[0][0]);   // [16][256]
    const int r = wave * 4 + g16;
    #pragma unroll
    for (int t = 0; t < 4; ++t) {
        lsf[r * 256 + 0 * 64 + t * 16 + c15] = psA0[t];
        lsf[r * 256 + 1 * 64 + t * 16 + c15] = psA1[t];
        lsf[r * 256 + 2 * 64 + t * 16 + c15] = psB0[t];
        lsf[r * 256 + 3 * 64 + t * 16 + c15] = psB1[t];
    }
    __syncthreads();
    const int tid = threadIdx.x;
    float s = 0.f;
    #pragma unroll
    for (int rr = 0; rr < 16; ++rr) s += lsf[rr * 256 + tid];
    part[(size_t)blockIdx.x * 256 + tid] = s;
}

// ---------- tile-paired conv2/conv4 (CIN=64 bf16, folded W, bf16 out) ----------
// Block handles tiles 2q, 2q+1 of ONE conv: weights shared, two chains.
__global__ __launch_bounds__(256, 3)
void conv24_kernel(const unsigned short* __restrict__ x2, const int* __restrict__ nbr2,
                   const float* __restrict__ tv2, const unsigned short* __restrict__ Wb2,
                   unsigned short* __restrict__ y2,
                   const unsigned short* __restrict__ x4, const int* __restrict__ nbr4,
                   const float* __restrict__ tv4, const unsigned short* __restrict__ Wb4,
                   unsigned short* __restrict__ y4,
                   float* __restrict__ part,    // [nb2][256]
                   int n_vox, int ntile, int nb2)
{
    const int lane = threadIdx.x & 63;
    const int wave = threadIdx.x >> 6;
    __shared__ __align__(16) char smem[4][4352];   // epilogue stage only
    char* my = smem[wave];
    const bool second = blockIdx.x >= nb2;
    const int q = second ? blockIdx.x - nb2 : blockIdx.x;
    const unsigned short* x = second ? x4 : x2;
    const int* nbr = second ? nbr4 : nbr2;
    const float* tvec = second ? tv4 : tv2;
    const unsigned short* Wb = second ? Wb4 : Wb2;
    unsigned short* yout = second ? y4 : y2;

    const int c15 = lane & 15, g16 = lane >> 4;
    const int j7 = lane & 7, kk = j7 + (j7 >= 4 ? 1 : 0), vv = lane >> 3;
    const int t0 = q * 2, t1 = q * 2 + 1;
    const bool valid1 = t1 < ntile;
    const int v16a = t0 * 64 + wave * 16;
    const int v16b = t1 * 64 + wave * 16;

    // probes for BOTH tiles first (longest chains, independent)
    int pa0 = nbr[(size_t)(v16a + vv) * 9 + kk];
    int pa1 = nbr[(size_t)(v16a + 8 + vv) * 9 + kk];
    int pb0 = n_vox, pb1 = n_vox;
    if (valid1) {
        pb0 = nbr[(size_t)(v16b + vv) * 9 + kk];
        pb1 = nbr[(size_t)(v16b + 8 + vv) * 9 + kk];
    }

    // dense A-frags for both tiles
    const unsigned short* xra = x + (size_t)(v16a + c15) * 64 + g16 * 8;
    bf16x8 a0a = *reinterpret_cast<const bf16x8*>(xra);
    bf16x8 a1a = *reinterpret_cast<const bf16x8*>(xra + 32);
    bf16x8 a0b = a0a, a1b = a1a;
    if (valid1) {
        const unsigned short* xrb = x + (size_t)(v16b + c15) * 64 + g16 * 8;
        a0b = *reinterpret_cast<const bf16x8*>(xrb);
        a1b = *reinterpret_cast<const bf16x8*>(xrb + 32);
    }

    // shared dense B-frags + tC
    bf16x8 bwC[2][4];
    #pragma unroll
    for (int kt = 0; kt < 2; ++kt)
        #pragma unroll
        for (int t = 0; t < 4; ++t)
            bwC[kt][t] = *reinterpret_cast<const bf16x8*>(Wb + (size_t)(((4*2+kt)*4+t)*64 + lane) * 8);

    f32x4 accA[4], accB[4];
    #pragma unroll
    for (int t = 0; t < 4; ++t) {
        float tC = tvec[4 * 64 + t * 16 + c15];
        f32x4 z = {tC, tC, tC, tC};
        accA[t] = z; accB[t] = z;
    }
    #pragma unroll
    for (int t = 0; t < 4; ++t) {
        accA[t] = __builtin_amdgcn_mfma_f32_16x16x32_bf16(a0a, bwC[0][t], accA[t], 0, 0, 0);
        accB[t] = __builtin_amdgcn_mfma_f32_16x16x32_bf16(a0b, bwC[0][t], accB[t], 0, 0, 0);
        accA[t] = __builtin_amdgcn_mfma_f32_16x16x32_bf16(a1a, bwC[1][t], accA[t], 0, 0, 0);
        accB[t] = __builtin_amdgcn_mfma_f32_16x16x32_bf16(a1b, bwC[1][t], accB[t], 0, 0, 0);
    }

    ull mA0 = __ballot(pa0 < n_vox), mA1 = __ballot(pa1 < n_vox);
    ull mB0 = __ballot(pb0 < n_vox), mB1 = __ballot(pb1 < n_vox);
    const int nhA = __popcll(mA0) + __popcll(mA1);
    const int nhB = __popcll(mB0) + __popcll(mB1);

    auto walksel = [&](ull M, int preg, int slot, int base, int& sel) {
        while (M) {
            int b = __builtin_ctzll(M); M &= M - 1;
            int src = __shfl(preg, b);
            sel = (c15 == slot - base) ? src : sel;
            ++slot;
        }
        return slot;
    };
    auto kloop = [&](ull m0, ull m1, bf16x8 h0, bf16x8 h1, f32x4* acc, int base) {
        const int pref = __popcll(m0);
        for (int tap = 0; tap < 8; ++tap) {
            ull TM = REP8 << tap;
            ull k0 = m0 & TM, k1 = m1 & TM;
            if (!(k0 | k1)) continue;
            int k = tap + (tap >= 4 ? 1 : 0);
            bf16x8 bk[2][4];
            #pragma unroll
            for (int kt = 0; kt < 2; ++kt)
                #pragma unroll
                for (int t = 0; t < 4; ++t)
                    bk[kt][t] = *reinterpret_cast<const bf16x8*>(Wb + (size_t)(((k*2+kt)*4+t)*64 + lane) * 8);
            float tvk[4];
            #pragma unroll
            for (int t = 0; t < 4; ++t) tvk[t] = tvec[k * 64 + t * 16 + c15];
            f32x4 ch[4];
            #pragma unroll
            for (int t = 0; t < 4; ++t) { f32x4 z = {0.f,0.f,0.f,0.f}; ch[t] = z; }
            #pragma unroll
            for (int t = 0; t < 4; ++t) {
                ch[t] = __builtin_amdgcn_mfma_f32_16x16x32_bf16(h0, bk[0][t], ch[t], 0, 0, 0);
                ch[t] = __builtin_amdgcn_mfma_f32_16x16x32_bf16(h1, bk[1][t], ch[t], 0, 0, 0);
            }
            auto inj = [&](ull M, ull msrc, int spref, int vbase) {
                while (M) {
                    int b = __builtin_ctzll(M); M &= M - 1;
                    int slot = spref + __popcll(msrc & ((1ull << b) - 1ull));
                    int rs = slot - base;
                    if (rs < 0 || rs >= 16) continue;
                    int vb = vbase + (b >> 3);
                    int srclane = ((rs >> 2) << 4) + c15;
                    int jj = rs & 3, gp = vb >> 2, jp = vb & 3;
                    float v0, v1, v2, v3;
                    switch (jj) {
                    case 0: v0=__shfl(ch[0][0],srclane); v1=__shfl(ch[1][0],srclane);
                            v2=__shfl(ch[2][0],srclane); v3=__shfl(ch[3][0],srclane); break;
                    case 1: v0=__shfl(ch[0][1],srclane); v1=__shfl(ch[1][1],srclane);
                            v2=__shfl(ch[2][1],srclane); v3=__shfl(ch[3][1],srclane); break;
                    case 2: v0=__shfl(ch[0][2],srclane); v1=__shfl(ch[1][2],srclane);
                            v2=__shfl(ch[2][2],srclane); v3=__shfl(ch[3][2],srclane); break;
                    default: v0=__shfl(ch[0][3],srclane); v1=__shfl(ch[1][3],srclane);
                             v2=__shfl(ch[2][3],srclane); v3=__shfl(ch[3][3],srclane); break;
                    }
                    bool mine = (g16 == gp);
                    float z0 = mine ? (v0 + tvk[0]) : 0.f, z1 = mine ? (v1 + tvk[1]) : 0.f;
                    float z2 = mine ? (v2 + tvk[2]) : 0.f, z3 = mine ? (v3 + tvk[3]) : 0.f;
                    switch (jp) {
                    case 0: acc[0][0]+=z0; acc[1][0]+=z1; acc[2][0]+=z2; acc[3][0]+=z3; break;
                    case 1: acc[0][1]+=z0; acc[1][1]+=z1; acc[2][1]+=z2; acc[3][1]+=z3; break;
                    case 2: acc[0][2]+=z0; acc[1][2]+=z1; acc[2][2]+=z2; acc[3][2]+=z3; break;
                    default: acc[0][3]+=z0; acc[1][3]+=z1; acc[2][3]+=z2; acc[3][3]+=z3; break;
                    }
                }
            };
            inj(k0, m0, 0, 0);
            inj(k1, m1, pref, 8);
        }
    };

    for (int base = 0; base < nhA; base += 16) {
        int sel = 0;
        int c0 = walksel(mA0, pa0, 0, base, sel);
        walksel(mA1, pa1, c0, base, sel);
        const unsigned short* hr = x + (size_t)sel * 64 + g16 * 8;
        bf16x8 h0 = *reinterpret_cast<const bf16x8*>(hr);
        bf16x8 h1 = *reinterpret_cast<const bf16x8*>(hr + 32);
        kloop(mA0, mA1, h0, h1, accA, base);
    }
    for (int base = 0; base < nhB; base += 16) {
        int sel = 0;
        int c0 = walksel(mB0, pb0, 0, base, sel);
        walksel(mB1, pb1, c0, base, sel);
        const unsigned short* hr = x + (size_t)sel * 64 + g16 * 8;
        bf16x8 h0 = *reinterpret_cast<const bf16x8*>(hr);
        bf16x8 h1 = *reinterpret_cast<const bf16x8*>(hr + 32);
        kloop(mB0, mB1, h0, h1, accB, base);
    }

    // epilogues (shared ps accumulators over both tiles)
    float ps0[4] = {0,0,0,0}, ps1[4] = {0,0,0,0};
    auto epi = [&](f32x4* acc, int v16) {
        float* stg = reinterpret_cast<float*>(my);
        #pragma unroll
        for (int t = 0; t < 4; ++t) {
            const int col = t * 16 + c15;
            #pragma unroll
            for (int j = 0; j < 4; ++j) {
                float v = acc[t][j];
                v = v > 0.f ? v : 0.01f * v;
                ps0[t] += v;
                ps1[t] = fmaf(v, v, ps1[t]);
                stg[(g16 * 4 + j) * 68 + col] = v;
            }
        }
        const int mm = lane >> 2, cc0 = (lane & 3) * 16;
        float4 q0 = *reinterpret_cast<float4*>(&stg[mm * 68 + cc0]);
        float4 q1 = *reinterpret_cast<float4*>(&stg[mm * 68 + cc0 + 4]);
        float4 q2 = *reinterpret_cast<float4*>(&stg[mm * 68 + cc0 + 8]);
        float4 q3 = *reinterpret_cast<float4*>(&stg[mm * 68 + cc0 + 12]);
        uint4 o0, o1;
        o0.x = pkbf(q0.x, q0.y); o0.y = pkbf(q0.z, q0.w);
        o0.z = pkbf(q1.x, q1.y); o0.w = pkbf(q1.z, q1.w);
        o1.x = pkbf(q2.x, q2.y); o1.y = pkbf(q2.z, q2.w);
        o1.z = pkbf(q3.x, q3.y); o1.w = pkbf(q3.z, q3.w);
        uint4* dst = reinterpret_cast<uint4*>(yout + (size_t)(v16 + mm) * 64 + cc0);
        dst[0] = o0; dst[1] = o1;
    };
    epi(accA, v16a);
    if (valid1) epi(accB, v16b);

    __syncthreads();
    float* lsf = reinterpret_cast<float*>(&smem[0][0]);   // [16][128]
    const int r = wave * 4 + g16;
    #pragma unroll
    for (int t = 0; t < 4; ++t) {
        lsf[r * 128 + t * 16 + c15] = ps0[t];
        lsf[r * 128 + 64 + t * 16 + c15] = ps1[t];
    }
    __syncthreads();
    const int tid = threadIdx.x;
    if (tid < 128) {
        float s = 0.f;
        #pragma unroll
        for (int rr = 0; rr < 16; ++rr) s += lsf[rr * 128 + tid];
        part[(size_t)q * 256 + (second ? 128 : 0) + tid] = s;
    }
}

// ---------- reduce partials + BN scale/shift (two layers per launch) ----------
__global__ void bnred_kernel(const float* __restrict__ part,   // [nblk][256]
                             const float* __restrict__ gA, const float* __restrict__ bA,
                             const float* __restrict__ gB, const float* __restrict__ bB,
                             float* __restrict__ scA, float* __restrict__ shA,
                             float* __restrict__ scB, float* __restrict__ shB,
                             float invN, int nblk)
{
    const int l = blockIdx.x >> 6, c = blockIdx.x & 63;   // grid 128
    const float* base = part + (size_t)(l * 2) * 64 + c;
    __shared__ float red[256][2];
    float s = 0.f, q = 0.f;
    for (int b = threadIdx.x; b < nblk; b += 256) {
        s += base[(size_t)b * 256];
        q += base[(size_t)b * 256 + 64];
    }
    red[threadIdx.x][0] = s; red[threadIdx.x][1] = q;
    __syncthreads();
    for (int off = 128; off; off >>= 1) {
        if (threadIdx.x < off) {
            red[threadIdx.x][0] += red[threadIdx.x + off][0];
            red[threadIdx.x][1] += red[threadIdx.x + off][1];
        }
        __syncthreads();
    }
    if (threadIdx.x == 0) {
        float m = red[0][0] * invN;
        float v = red[0][1] * invN - m * m;
        const float* g = l ? gB : gA;
        const float* bb = l ? bB : bA;
        float* sc = l ? scB : scA;
        float* sh = l ? shB : shA;
        float scale = g[c] / sqrtf(v + EPSF);
        sc[c] = scale;
        sh[c] = bb[c] - m * scale;
    }
}

// ---------- fold BN1/BN3 into W2/W4: tvec + bf16 B-frags for ALL 9 ks ----------
__global__ void foldpack_kernel(const float* __restrict__ W2, const float* __restrict__ W4,
                                const float* __restrict__ sc1, const float* __restrict__ sh1,
                                const float* __restrict__ sc3, const float* __restrict__ sh3,
                                float* __restrict__ t2, float* __restrict__ t4,
                                unsigned short* __restrict__ Wb2, unsigned short* __restrict__ Wb4)
{
    int i = blockIdx.x * 256 + threadIdx.x;
    if (i < 2 * 9 * 64) {
        const float* W = i < 9 * 64 ? W2 : W4;
        const float* shift = i < 9 * 64 ? sh1 : sh3;
        float* tv = i < 9 * 64 ? t2 : t4;
        int ii = i < 9 * 64 ? i : i - 9 * 64;
        int d = ii & 63, k = ii >> 6;
        float t = 0.f;
        for (int c = 0; c < 64; ++c)
            t = fmaf(shift[c], W[((size_t)k * 64 + c) * 64 + d], t);
        tv[ii] = t;
    } else {
        int p = i - 2 * 9 * 64;
        if (p >= 2 * 9 * 4096) return;
        const float* W = p < 9 * 4096 ? W2 : W4;
        const float* scale = p < 9 * 4096 ? sc1 : sc3;
        unsigned short* Wb = p < 9 * 4096 ? Wb2 : Wb4;
        int pp = p < 9 * 4096 ? p : p - 9 * 4096;
        int k = pp >> 12, rest = pp & 4095;
        int kt = rest >> 11, t = (rest >> 9) & 3, lane = (rest >> 3) & 63, j = rest & 7;
        int c = kt * 32 + (lane >> 4) * 8 + j;
        int d = t * 16 + (lane & 15);
        Wb[pp] = f2bf(scale[c] * W[((size_t)k * 64 + c) * 64 + d]);
    }
}

// ---------- final: out = BN2(y2) + BN4(y4), bf16 in, fp32 out ----------
__global__ void final_kernel(const unsigned short* __restrict__ y2,
                             const unsigned short* __restrict__ y4,
                             const float* __restrict__ sc2, const float* __restrict__ sh2,
                             const float* __restrict__ sc4, const float* __restrict__ sh4,
                             float* __restrict__ out, int n8)
{
    int i = blockIdx.x * 256 + threadIdx.x;
    if (i >= n8) return;
    const int c0 = (i & 7) * 8;
    uint4 aq = *reinterpret_cast<const uint4*>(y2 + (size_t)i * 8);
    uint4 bq = *reinterpret_cast<const uint4*>(y4 + (size_t)i * 8);
    float a[8], b[8];
    a[0] = __uint_as_float(aq.x << 16); a[1] = __uint_as_float(aq.x & 0xffff0000u);
    a[2] = __uint_as_float(aq.y << 16); a[3] = __uint_as_float(aq.y & 0xffff0000u);
    a[4] = __uint_as_float(aq.z << 16); a[5] = __uint_as_float(aq.z & 0xffff0000u);
    a[6] = __uint_as_float(aq.w << 16); a[7] = __uint_as_float(aq.w & 0xffff0000u);
    b[0] = __uint_as_float(bq.x << 16); b[1] = __uint_as_float(bq.x & 0xffff0000u);
    b[2] = __uint_as_float(bq.y << 16); b[3] = __uint_as_float(bq.y & 0xffff0000u);
    b[4] = __uint_as_float(bq.z << 16); b[5] = __uint_as_float(bq.z & 0xffff0000u);
    b[6] = __uint_as_float(bq.w << 16); b[7] = __uint_as_float(bq.w & 0xffff0000u);
    float r[8];
    #pragma unroll
    for (int j = 0; j < 8; ++j)
        r[j] = fmaf(a[j], sc2[c0 + j], sh2[c0 + j]) + fmaf(b[j], sc4[c0 + j], sh4[c0 + j]);
    float4 o0 = {r[0], r[1], r[2], r[3]};
    float4 o1 = {r[4], r[5], r[6], r[7]};
    float* po = out + (size_t)i * 8;
    *reinterpret_cast<float4*>(po) = o0;
    *reinterpret_cast<float4*>(po + 4) = o1;
}

extern "C" void kernel_launch(void* const* d_in, const int* in_sizes, int n_in,
                              void* d_out, int out_size, void* d_ws, size_t ws_size,
                              hipStream_t stream)
{
    const float* feats  = (const float*)d_in[0];
    const int*   nbr133 = (const int*)d_in[1];
    const int*   nbr313 = (const int*)d_in[2];
    const float* W1 = (const float*)d_in[3];
    const float* W2 = (const float*)d_in[4];
    const float* W3 = (const float*)d_in[5];
    const float* W4 = (const float*)d_in[6];
    const float* g0  = (const float*)d_in[7];
    const float* b0  = (const float*)d_in[8];
    const float* g02 = (const float*)d_in[9];
    const float* b02 = (const float*)d_in[10];
    const float* g1  = (const float*)d_in[11];
    const float* b1  = (const float*)d_in[12];
    const float* g2  = (const float*)d_in[13];
    const float* b2  = (const float*)d_in[14];

    const int N = in_sizes[0] / 32;
    const int ntile = N >> 6;                         // 3125 for N=200000
    const int nb2 = (ntile + 1) / 2;                  // 1563

    char* w = (char*)d_ws;
    auto alloc = [&](size_t bytes) {
        char* p = w;
        w += (bytes + 255) & ~(size_t)255;
        return p;
    };
    unsigned short* y1 = (unsigned short*)alloc((size_t)N * 64 * 2);
    unsigned short* y3 = (unsigned short*)alloc((size_t)N * 64 * 2);
    unsigned short* y2 = (unsigned short*)alloc((size_t)N * 64 * 2);
    unsigned short* y4 = (unsigned short*)alloc((size_t)N * 64 * 2);
    float* t2 = (float*)alloc(9 * 64 * 4);
    float* t4 = (float*)alloc(9 * 64 * 4);
    unsigned short* Wb1 = (unsigned short*)alloc(9 * 4 * 64 * 8 * 2);
    unsigned short* Wb3 = (unsigned short*)alloc(9 * 4 * 64 * 8 * 2);
    unsigned short* Wb2 = (unsigned short*)alloc(9 * 2 * 4 * 64 * 8 * 2);
    unsigned short* Wb4 = (unsigned short*)alloc(9 * 2 * 4 * 64 * 8 * 2);
    float* part13 = (float*)alloc((size_t)ntile * 256 * 4);
    float* part24 = (float*)alloc((size_t)ntile * 256 * 4);
    float* scl = (float*)alloc(8 * 64 * 4);
    float *sc1 = scl,       *sh1 = scl + 64;
    float *sc3 = scl + 128, *sh3 = scl + 192;
    float *sc2 = scl + 256, *sh2 = scl + 320;
    float *sc4 = scl + 384, *sh4 = scl + 448;

    const float invN = 1.0f / (float)N;

    prep_kernel<<<(2 * 9 * 2048 + 255) / 256, 256, 0, stream>>>(W1, W3, Wb1, Wb3);

    conv13_kernel<<<ntile, 256, 0, stream>>>(feats, nbr133, nbr313, Wb1, Wb3,
                                             y1, y3, part13, N);
    bnred_kernel<<<128, 256, 0, stream>>>(part13, g0, b0, g1, b1,
                                          sc1, sh1, sc3, sh3, invN, ntile);
    foldpack_kernel<<<(2 * 9 * 64 + 2 * 9 * 4096 + 255) / 256, 256, 0, stream>>>(
        W2, W4, sc1, sh1, sc3, sh3, t2, t4, Wb2, Wb4);

    conv24_kernel<<<2 * nb2, 256, 0, stream>>>(y1, nbr313, t2, Wb2, y2,
                                               y3, nbr133, t4, Wb4, y4,
                                               part24, N, ntile, nb2);
    bnred_kernel<<<128, 256, 0, stream>>>(part24, g02, b02, g2, b2,
                                          sc2, sh2, sc4, sh4, invN, nb2);

    final_kernel<<<(N * 8 + 255) / 256, 256, 0, stream>>>(
        y2, y4, sc2, sh2, sc4, sh4, (float*)d_out, N * 8);
}